// Round 3
// baseline (2329.108 us; speedup 1.0000x reference)
//
#include <hip/hip_runtime.h>

typedef unsigned short u16;
typedef unsigned int u32;
typedef __bf16 bf16x8 __attribute__((ext_vector_type(8)));
typedef float f32x4 __attribute__((ext_vector_type(4)));
typedef u16 u16x8 __attribute__((ext_vector_type(8)));
typedef u16 u16x4 __attribute__((ext_vector_type(4)));

static __device__ __forceinline__ u16 f2bf(float f) {
  u32 u = __builtin_bit_cast(u32, f);
  u32 r = (u + 0x7FFFu + ((u >> 16) & 1u)) >> 16;  // RNE; inputs finite
  return (u16)r;
}

#define GLOAD_LDS16(gp, lp)                                                   \
  __builtin_amdgcn_global_load_lds(                                           \
      (const __attribute__((address_space(1))) void*)(gp),                    \
      (__attribute__((address_space(3))) void*)(lp), 16, 0, 0)

// ---------------- embedding: x = tok_emb[idx] + pos_emb ----------------
__global__ void k_embed(const int* __restrict__ idx, const float* __restrict__ tok,
                        const float* __restrict__ pos, float* __restrict__ x) {
  int row = blockIdx.x;            // b*1024 + t
  int t = row & 1023;
  int id = idx[row];
  int c = threadIdx.x * 4;
  float4 a = *(const float4*)(tok + (size_t)id * 1024 + c);
  float4 p = *(const float4*)(pos + (size_t)t * 1024 + c);
  float4 r{a.x + p.x, a.y + p.y, a.z + p.z, a.w + p.w};
  *(float4*)(x + (size_t)row * 1024 + c) = r;
}

// ---------------- layernorm (f32 in) -> bf16 out ----------------
__global__ void k_ln(const float* __restrict__ x, const float* __restrict__ sc,
                     const float* __restrict__ bi, u16* __restrict__ out) {
  int row = blockIdx.x;
  int t = threadIdx.x;
  const float* xr = x + (size_t)row * 1024;
  float4 v = *(const float4*)(xr + t * 4);
  float s = v.x + v.y + v.z + v.w;
  float ss = v.x * v.x + v.y * v.y + v.z * v.z + v.w * v.w;
  for (int d = 1; d < 64; d <<= 1) { s += __shfl_xor(s, d); ss += __shfl_xor(ss, d); }
  __shared__ float red[8];
  int wave = t >> 6, lane = t & 63;
  if (lane == 0) { red[wave] = s; red[wave + 4] = ss; }
  __syncthreads();
  s = red[0] + red[1] + red[2] + red[3];
  ss = red[4] + red[5] + red[6] + red[7];
  float mu = s * (1.0f / 1024.0f);
  float var = ss * (1.0f / 1024.0f) - mu * mu;
  float inv = rsqrtf(var + 1e-5f);
  float4 g = *(const float4*)(sc + t * 4);
  float4 b = *(const float4*)(bi + t * 4);
  u16x4 o;
  o[0] = f2bf((v.x - mu) * inv * g.x + b.x);
  o[1] = f2bf((v.y - mu) * inv * g.y + b.y);
  o[2] = f2bf((v.z - mu) * inv * g.z + b.z);
  o[3] = f2bf((v.w - mu) * inv * g.w + b.w);
  *(u16x4*)(out + (size_t)row * 1024 + t * 4) = o;
}

// ---------------- transpose+convert: f32 src[R][C] -> bf16 dst[C][R] ----------------
__launch_bounds__(1024)
__global__ void k_transpose(const float* __restrict__ src, u16* __restrict__ dst,
                            int R, int C) {
  __shared__ float tile[32][33];
  int tx = threadIdx.x, ty = threadIdx.y;
  int c = blockIdx.x * 32 + tx;
  int r = blockIdx.y * 32 + ty;
  tile[ty][tx] = src[(size_t)r * C + c];
  __syncthreads();
  int dr = blockIdx.x * 32 + ty;   // dst row = src col
  int dc = blockIdx.y * 32 + tx;   // dst col = src row
  dst[(size_t)dr * R + dc] = f2bf(tile[tx][ty]);
}

// ---------------- GEMM 128x128 (2-phase): C = A x Bt^T ----------------
enum { EPI_QKV = 0, EPI_RES = 1, EPI_RELU = 2, EPI_OUT = 3 };

template <int EPI>
__launch_bounds__(256, 4)
__global__ void k_gemm(const u16* __restrict__ A, const u16* __restrict__ Bt,
                       const float* __restrict__ bias, float* __restrict__ fout,
                       u16* __restrict__ bout, int M, int N, int K) {
  __shared__ alignas(16) u16 sm[2][2][128][32];
  const int t = threadIdx.x;
  const int wave = t >> 6, lane = t & 63;
  const int wm = wave >> 1, wn = wave & 1;
  const int g = lane >> 4, c = lane & 15;
  const int m0 = blockIdx.x * 128, n0 = blockIdx.y * 128;

  const int srow = wave * 32 + (lane >> 2);
  const int sseg = (lane & 3) * 8;
  const u16* gA = A + (size_t)(m0 + srow) * K + sseg;
  const u16* gB = Bt + (size_t)(n0 + srow) * K + sseg;

  f32x4 acc[4][4] = {};

  const int nK = K >> 5;
  int cur = 0;

#pragma unroll
  for (int p = 0; p < 2; ++p) {
    GLOAD_LDS16(gA + (size_t)p * 16 * K, &sm[0][0][wave * 32 + p * 16][0]);
    GLOAD_LDS16(gB + (size_t)p * 16 * K, &sm[0][1][wave * 32 + p * 16][0]);
  }
  __syncthreads();

  for (int kt = 0; kt < nK; ++kt) {
    if (kt + 1 < nK) {
      const int k0 = (kt + 1) << 5;
#pragma unroll
      for (int p = 0; p < 2; ++p) {
        GLOAD_LDS16(gA + k0 + (size_t)p * 16 * K, &sm[cur ^ 1][0][wave * 32 + p * 16][0]);
        GLOAD_LDS16(gB + k0 + (size_t)p * 16 * K, &sm[cur ^ 1][1][wave * 32 + p * 16][0]);
      }
    }
    bf16x8 af[4], bfr[4];
#pragma unroll
    for (int i = 0; i < 4; ++i) {
      af[i]  = *(const bf16x8*)&sm[cur][0][wm * 64 + i * 16 + c][g * 8];
      bfr[i] = *(const bf16x8*)&sm[cur][1][wn * 64 + i * 16 + c][g * 8];
    }
#pragma unroll
    for (int i = 0; i < 4; ++i)
#pragma unroll
      for (int j = 0; j < 4; ++j)
        acc[i][j] = __builtin_amdgcn_mfma_f32_16x16x32_bf16(af[i], bfr[j], acc[i][j], 0, 0, 0);
    __syncthreads();
    cur ^= 1;
  }

#pragma unroll
  for (int i = 0; i < 4; ++i) {
#pragma unroll
    for (int j = 0; j < 4; ++j) {
#pragma unroll
      for (int r = 0; r < 4; ++r) {
        int m = m0 + wm * 64 + i * 16 + g * 4 + r;
        int n = n0 + wn * 64 + j * 16 + c;
        float v = acc[i][j][r];
        if (EPI == EPI_QKV) {
          int which = n >> 10;
          int hh = (n >> 6) & 15, f = n & 63;
          int b = m >> 10, tt = m & 1023;
          bout[(size_t)which * 2097152 +
               ((size_t)(b * 16 + hh) * 1024 + tt) * 64 + f] = f2bf(v);
        } else if (EPI == EPI_RES) {
          size_t off = (size_t)m * N + n;
          fout[off] += v + bias[n];
        } else if (EPI == EPI_RELU) {
          float u = v + bias[n];
          bout[(size_t)m * N + n] = f2bf(u > 0.f ? u : 0.f);
        }
      }
    }
  }
}

// ---------------- GEMM 256x256 8-phase (LM head, f32+bias out) ----------------
// BK=64, 8 waves (2Mx4N, interleaved halves), LDS 128KB double-buffered,
// T2 XOR-swizzle (pre-swizzled gload source + swizzled ds_read),
// counted vmcnt(4) at phases 4/8, raw s_barrier, setprio around MFMA.

#define BARRIER_ASM asm volatile("s_barrier" ::: "memory")
#define VM4 asm volatile("s_waitcnt vmcnt(4)" ::: "memory")
#define VM0 asm volatile("s_waitcnt vmcnt(0)" ::: "memory")

#define STGA(sl, hf, kt)                                                       \
  {                                                                            \
    _Pragma("unroll") for (int p = 0; p < 2; ++p) {                            \
      int idx = p * 512 + t, rw = idx >> 3, sg = idx & 7;                      \
      GLOAD_LDS16(A + (size_t)(m0 + (hf)*128 + rw) * K + (kt)*64 +             \
                      ((sg ^ (rw & 7)) << 3),                                  \
                  &Alds[sl][(hf)*128 + rw][sg << 3]);                          \
    }                                                                          \
  }
#define STGB(sl, hf, kt)                                                       \
  {                                                                            \
    _Pragma("unroll") for (int p = 0; p < 2; ++p) {                            \
      int idx = p * 512 + t, rw = idx >> 3, sg = idx & 7;                      \
      GLOAD_LDS16(Bt + (size_t)(n0 + (hf)*128 + rw) * K + (kt)*64 +            \
                      ((sg ^ (rw & 7)) << 3),                                  \
                  &Blds[sl][(hf)*128 + rw][sg << 3]);                          \
    }                                                                          \
  }

#define PHASE(mh, nh, sl, STAGE_STMTS, VMWAIT)                                 \
  {                                                                            \
    bf16x8 af[4][2], bfm[2][2];                                                \
    _Pragma("unroll") for (int i = 0; i < 4; ++i) {                            \
      int ra = (mh)*128 + wm * 64 + i * 16 + c;                                \
      _Pragma("unroll") for (int ks = 0; ks < 2; ++ks)                         \
        af[i][ks] = *(const bf16x8*)&Alds[sl][ra][(((ks << 2) | g) ^ (ra & 7)) << 3]; \
    }                                                                          \
    _Pragma("unroll") for (int j = 0; j < 2; ++j) {                            \
      int rb = (nh)*128 + wn * 32 + j * 16 + c;                                \
      _Pragma("unroll") for (int ks = 0; ks < 2; ++ks)                         \
        bfm[j][ks] = *(const bf16x8*)&Blds[sl][rb][(((ks << 2) | g) ^ (rb & 7)) << 3]; \
    }                                                                          \
    STAGE_STMTS;                                                               \
    BARRIER_ASM;                                                               \
    __builtin_amdgcn_s_setprio(1);                                             \
    _Pragma("unroll") for (int i = 0; i < 4; ++i)                              \
      _Pragma("unroll") for (int j = 0; j < 2; ++j)                            \
        _Pragma("unroll") for (int ks = 0; ks < 2; ++ks)                       \
          acc[mh][nh][i][j] = __builtin_amdgcn_mfma_f32_16x16x32_bf16(         \
              af[i][ks], bfm[j][ks], acc[mh][nh][i][j], 0, 0, 0);              \
    __builtin_amdgcn_s_setprio(0);                                             \
    VMWAIT;                                                                    \
    BARRIER_ASM;                                                               \
  }

__launch_bounds__(512, 2)
__global__ void k_gemm_lm(const u16* __restrict__ A, const u16* __restrict__ Bt,
                          const float* __restrict__ bias, float* __restrict__ fout,
                          int M, int N, int K) {
  __shared__ alignas(16) u16 Alds[2][256][64];
  __shared__ alignas(16) u16 Blds[2][256][64];
  const int t = threadIdx.x;
  const int wid = t >> 6, lane = t & 63;
  const int wm = wid >> 2, wn = wid & 3;
  const int g = lane >> 4, c = lane & 15;

  // XCD-aware swizzle (nwg = 8*125 = 1000, 1000 % 8 == 0 -> simple bijection)
  int bid = blockIdx.x;
  int swz = (bid & 7) * 125 + (bid >> 3);
  const int m0 = (swz & 7) * 256, n0 = (swz >> 3) * 256;

  f32x4 acc[2][2][4][2] = {};

  const int nK = K >> 6;          // K-tiles of 64
  const int nIter = nK >> 1;      // 2 K-tiles per iteration

  // prologue: tile0 (slot0) all halves; tile1 (slot1) A-h0, B-h0
  STGA(0, 0, 0); STGB(0, 0, 0);
  STGA(0, 1, 0); STGB(0, 1, 0);
  STGA(1, 0, 1); STGB(1, 0, 1);
  VM4;            // tile0's 4 half-tiles (8 oldest loads) landed
  BARRIER_ASM;

  for (int it = 0; it < nIter; ++it) {
    const int t1 = 2 * it + 1, t2 = 2 * it + 2, t3 = 2 * it + 3;
    const bool more = (it + 1 < nIter);
    // phases 1-4: compute tile 2it (slot0)
    PHASE(0, 0, 0, { STGA(1, 1, t1); }, );
    PHASE(0, 1, 0, { STGB(1, 1, t1); }, );
    PHASE(1, 0, 0, { if (more) STGA(0, 0, t2); }, );
    if (more) { PHASE(1, 1, 0, { STGB(0, 0, t2); }, VM4); }
    else      { PHASE(1, 1, 0, { }, VM0); }
    // phases 5-8: compute tile 2it+1 (slot1)
    PHASE(0, 0, 1, { if (more) STGA(0, 1, t2); }, );
    PHASE(0, 1, 1, { if (more) STGB(0, 1, t2); }, );
    PHASE(1, 0, 1, { if (more) STGA(1, 0, t3); }, );
    if (more) { PHASE(1, 1, 1, { STGB(1, 0, t3); }, VM4); }
    else      { PHASE(1, 1, 1, { }, VM0); }
  }

  // epilogue: LDS-staged coalesced f32 stores, 8 chunks of 32 rows x 256 cols
  float (*stile)[260] = (float(*)[260])&Alds[0][0][0];  // 33.3KB, within Alds
#pragma unroll 1
  for (int RG = 0; RG < 8; ++RG) {
    const int mh = RG >> 2, wsel = (RG >> 1) & 1, ih = RG & 1;
    if (wm == wsel) {
#pragma unroll
      for (int i2 = 0; i2 < 2; ++i2)
#pragma unroll
        for (int nh = 0; nh < 2; ++nh)
#pragma unroll
          for (int j = 0; j < 2; ++j)
#pragma unroll
            for (int r = 0; r < 4; ++r) {
              // static acc indexing: i = ih*2 + i2 resolved per (RG,i2) at compile time
              float v = ih ? acc[mh][nh][2 + i2][j][r] : acc[mh][nh][i2][j][r];
              stile[i2 * 16 + g * 4 + r][nh * 128 + wn * 32 + j * 16 + c] = v;
            }
    }
    __syncthreads();
    {
      int row = t >> 4, seg = t & 15;
      int m = m0 + RG * 32 + row;
      float* dst = fout + (size_t)m * N + n0 + seg * 16;
      const float* bsrc = bias + n0 + seg * 16;
#pragma unroll
      for (int q = 0; q < 4; ++q) {
        float4 v = *(const float4*)&stile[row][seg * 16 + q * 4];
        float4 bb = *(const float4*)&bsrc[q * 4];
        float4 o{v.x + bb.x, v.y + bb.y, v.z + bb.z, v.w + bb.w};
        *(float4*)(dst + q * 4) = o;
      }
    }
    __syncthreads();
  }
}

// ---------------- flash attention: 1 wave per (bh, 16 q-rows) ----------------
__launch_bounds__(64)
__global__ void k_attn(const u16* __restrict__ Q, const u16* __restrict__ Kb,
                       const u16* __restrict__ V, u16* __restrict__ O) {
  const int qb = blockIdx.x;       // 0..63
  const int bh = blockIdx.y;       // 0..31
  const int lane = threadIdx.x;
  const int g = lane >> 4, c = lane & 15;
  const int q0 = qb << 4;
  const u16* Qh = Q + (size_t)bh * 65536;
  const u16* Kh = Kb + (size_t)bh * 65536;
  const u16* Vh = V + (size_t)bh * 65536;

  __shared__ u16 Vt[64][40];
  __shared__ u16 Pl[16][40];

  const bf16x8 aq0 = *(const bf16x8*)(Qh + (q0 + c) * 64 + g * 8);
  const bf16x8 aq1 = *(const bf16x8*)(Qh + (q0 + c) * 64 + 32 + g * 8);

  f32x4 Oacc[4] = {};
  float Mr[4] = {-1e30f, -1e30f, -1e30f, -1e30f};
  float Lr[4] = {};

  const int nIt = (qb >> 1) + 1;
  for (int it = 0; it < nIt; ++it) {
    const int k0 = it << 5;
    f32x4 S0 = {}, S1 = {};
    {
      bf16x8 b0 = *(const bf16x8*)(Kh + (k0 + c) * 64 + g * 8);
      bf16x8 b1 = *(const bf16x8*)(Kh + (k0 + c) * 64 + 32 + g * 8);
      S0 = __builtin_amdgcn_mfma_f32_16x16x32_bf16(aq0, b0, S0, 0, 0, 0);
      S0 = __builtin_amdgcn_mfma_f32_16x16x32_bf16(aq1, b1, S0, 0, 0, 0);
      bf16x8 b2 = *(const bf16x8*)(Kh + (k0 + 16 + c) * 64 + g * 8);
      bf16x8 b3 = *(const bf16x8*)(Kh + (k0 + 16 + c) * 64 + 32 + g * 8);
      S1 = __builtin_amdgcn_mfma_f32_16x16x32_bf16(aq0, b2, S1, 0, 0, 0);
      S1 = __builtin_amdgcn_mfma_f32_16x16x32_bf16(aq1, b3, S1, 0, 0, 0);
    }
#pragma unroll
    for (int p = 0; p < 4; ++p) {
      int key = (p << 3) + (lane >> 3);
      int d0 = (lane & 7) << 3;
      u16x8 vv = *(const u16x8*)(Vh + (size_t)(k0 + key) * 64 + d0);
#pragma unroll
      for (int j = 0; j < 8; ++j) Vt[d0 + j][key] = vv[j];
    }
    const float scale = 0.125f;
#pragma unroll
    for (int r = 0; r < 4; ++r) {
      int q = q0 + (g << 2) + r;
      float s0 = (k0 + c <= q) ? S0[r] * scale : -1e30f;
      float s1 = (k0 + 16 + c <= q) ? S1[r] * scale : -1e30f;
      float m = fmaxf(s0, s1);
      m = fmaxf(m, __shfl_xor(m, 1));
      m = fmaxf(m, __shfl_xor(m, 2));
      m = fmaxf(m, __shfl_xor(m, 4));
      m = fmaxf(m, __shfl_xor(m, 8));
      float mnew = fmaxf(Mr[r], m);
      float p0 = expf(s0 - mnew);
      float p1 = expf(s1 - mnew);
      float rs = p0 + p1;
      rs += __shfl_xor(rs, 1);
      rs += __shfl_xor(rs, 2);
      rs += __shfl_xor(rs, 4);
      rs += __shfl_xor(rs, 8);
      float alpha = expf(Mr[r] - mnew);
      Lr[r] = Lr[r] * alpha + rs;
      Mr[r] = mnew;
#pragma unroll
      for (int nb = 0; nb < 4; ++nb) Oacc[nb][r] *= alpha;
      Pl[(g << 2) + r][c] = f2bf(p0);
      Pl[(g << 2) + r][16 + c] = f2bf(p1);
    }
    bf16x8 ap = *(const bf16x8*)&Pl[c][g * 8];
#pragma unroll
    for (int nb = 0; nb < 4; ++nb) {
      bf16x8 bv = *(const bf16x8*)&Vt[nb * 16 + c][g * 8];
      Oacc[nb] = __builtin_amdgcn_mfma_f32_16x16x32_bf16(ap, bv, Oacc[nb], 0, 0, 0);
    }
  }
  const int b = bh >> 4, hh = bh & 15;
#pragma unroll
  for (int r = 0; r < 4; ++r) {
    int tt = q0 + (g << 2) + r;
    float invl = 1.0f / Lr[r];
#pragma unroll
    for (int nb = 0; nb < 4; ++nb) {
      int d = nb * 16 + c;
      O[((size_t)(b * 1024 + tt)) * 1024 + hh * 64 + d] = f2bf(Oacc[nb][r] * invl);
    }
  }
}

// ---------------- launch ----------------
extern "C" void kernel_launch(void* const* d_in, const int* in_sizes, int n_in,
                              void* d_out, int out_size, void* d_ws, size_t ws_size,
                              hipStream_t stream) {
  const int*   idx  = (const int*)d_in[0];
  const float* tok  = (const float*)d_in[1];
  const float* pos  = (const float*)d_in[2];
  const float* Wq   = (const float*)d_in[3];
  const float* Wk   = (const float*)d_in[4];
  const float* Wv   = (const float*)d_in[5];
  const float* Wo   = (const float*)d_in[6];
  const float* bo   = (const float*)d_in[7];
  const float* ln1s = (const float*)d_in[8];
  const float* ln1b = (const float*)d_in[9];
  const float* ln2s = (const float*)d_in[10];
  const float* ln2b = (const float*)d_in[11];
  const float* W1   = (const float*)d_in[12];
  const float* b1   = (const float*)d_in[13];
  const float* W2   = (const float*)d_in[14];
  const float* b2   = (const float*)d_in[15];
  const float* lnfs = (const float*)d_in[16];
  const float* lnfb = (const float*)d_in[17];
  const float* Wlm  = (const float*)d_in[18];
  const float* blm  = (const float*)d_in[19];
  float* out = (float*)d_out;

  char* w = (char*)d_ws;
  auto alloc = [&](size_t bytes) {
    char* p = w;
    w += (bytes + 255) & ~(size_t)255;
    return p;
  };
  float* x  = (float*)alloc(2048ull * 1024 * 4);
  u16* h    = (u16*)alloc(2048ull * 1024 * 2);
  u16* qkv  = (u16*)alloc(3ull * 2097152 * 2);
  u16* o    = (u16*)alloc(2048ull * 1024 * 2);
  u16* a1   = (u16*)alloc(2048ull * 4096 * 2);
  u16* arena = (u16*)alloc(32000ull * 1024 * 2);

  dim3 b32(32, 32, 1);

  k_embed<<<2048, 256, 0, stream>>>(idx, tok, pos, x);

  for (int l = 0; l < 4; ++l) {
    u16* qkvT = arena;
    u16* WoT  = arena + 3ull * 1048576;
    u16* W1T  = arena + 4ull * 1048576;
    u16* W2T  = arena + 8ull * 1048576;
    k_transpose<<<dim3(32, 32), b32, 0, stream>>>(Wq + (size_t)l * 1048576, qkvT,            1024, 1024);
    k_transpose<<<dim3(32, 32), b32, 0, stream>>>(Wk + (size_t)l * 1048576, qkvT + 1048576,  1024, 1024);
    k_transpose<<<dim3(32, 32), b32, 0, stream>>>(Wv + (size_t)l * 1048576, qkvT + 2097152,  1024, 1024);
    k_transpose<<<dim3(32, 32), b32, 0, stream>>>(Wo + (size_t)l * 1048576, WoT, 1024, 1024);
    k_transpose<<<dim3(128, 32), b32, 0, stream>>>(W1 + (size_t)l * 4194304, W1T, 1024, 4096);
    k_transpose<<<dim3(32, 128), b32, 0, stream>>>(W2 + (size_t)l * 4194304, W2T, 4096, 1024);

    k_ln<<<2048, 256, 0, stream>>>(x, ln1s + l * 1024, ln1b + l * 1024, h);
    k_gemm<EPI_QKV><<<dim3(16, 24), 256, 0, stream>>>(h, qkvT, nullptr, nullptr, qkv,
                                                      2048, 3072, 1024);
    k_attn<<<dim3(64, 32), 64, 0, stream>>>(qkv, qkv + 2097152, qkv + 2 * 2097152, o);
    k_gemm<EPI_RES><<<dim3(16, 8), 256, 0, stream>>>(o, WoT, bo + l * 1024, x, nullptr,
                                                     2048, 1024, 1024);
    k_ln<<<2048, 256, 0, stream>>>(x, ln2s + l * 1024, ln2b + l * 1024, h);
    k_gemm<EPI_RELU><<<dim3(16, 32), 256, 0, stream>>>(h, W1T, b1 + l * 4096, nullptr, a1,
                                                       2048, 4096, 1024);
    k_gemm<EPI_RES><<<dim3(16, 8), 256, 0, stream>>>(a1, W2T, b2 + l * 1024, x, nullptr,
                                                     2048, 1024, 4096);
  }

  k_ln<<<2048, 256, 0, stream>>>(x, lnfs, lnfb, h);
  k_transpose<<<dim3(1000, 32), b32, 0, stream>>>(Wlm, arena, 1024, 32000);
  k_gemm_lm<<<1000, 512, 0, stream>>>(h, arena, blm, out, 2048, 32000, 1024);
}

// Round 4
// 1504.013 us; speedup vs baseline: 1.5486x; 1.5486x over previous
//
#include <hip/hip_runtime.h>

typedef unsigned short u16;
typedef unsigned int u32;
typedef __bf16 bf16x8 __attribute__((ext_vector_type(8)));
typedef float f32x4 __attribute__((ext_vector_type(4)));
typedef u16 u16x8 __attribute__((ext_vector_type(8)));
typedef u16 u16x4 __attribute__((ext_vector_type(4)));

static __device__ __forceinline__ u16 f2bf(float f) {
  u32 u = __builtin_bit_cast(u32, f);
  u32 r = (u + 0x7FFFu + ((u >> 16) & 1u)) >> 16;  // RNE; inputs finite
  return (u16)r;
}

#define GLOAD_LDS16(gp, lp)                                                   \
  __builtin_amdgcn_global_load_lds(                                           \
      (const __attribute__((address_space(1))) void*)(gp),                    \
      (__attribute__((address_space(3))) void*)(lp), 16, 0, 0)

// ---------------- embedding: x = tok_emb[idx] + pos_emb ----------------
__global__ void k_embed(const int* __restrict__ idx, const float* __restrict__ tok,
                        const float* __restrict__ pos, float* __restrict__ x) {
  int row = blockIdx.x;            // b*1024 + t
  int t = row & 1023;
  int id = idx[row];
  int c = threadIdx.x * 4;
  float4 a = *(const float4*)(tok + (size_t)id * 1024 + c);
  float4 p = *(const float4*)(pos + (size_t)t * 1024 + c);
  float4 r{a.x + p.x, a.y + p.y, a.z + p.z, a.w + p.w};
  *(float4*)(x + (size_t)row * 1024 + c) = r;
}

// ---------------- layernorm (f32 in) -> bf16 out ----------------
__global__ void k_ln(const float* __restrict__ x, const float* __restrict__ sc,
                     const float* __restrict__ bi, u16* __restrict__ out) {
  int row = blockIdx.x;
  int t = threadIdx.x;
  const float* xr = x + (size_t)row * 1024;
  float4 v = *(const float4*)(xr + t * 4);
  float s = v.x + v.y + v.z + v.w;
  float ss = v.x * v.x + v.y * v.y + v.z * v.z + v.w * v.w;
  for (int d = 1; d < 64; d <<= 1) { s += __shfl_xor(s, d); ss += __shfl_xor(ss, d); }
  __shared__ float red[8];
  int wave = t >> 6, lane = t & 63;
  if (lane == 0) { red[wave] = s; red[wave + 4] = ss; }
  __syncthreads();
  s = red[0] + red[1] + red[2] + red[3];
  ss = red[4] + red[5] + red[6] + red[7];
  float mu = s * (1.0f / 1024.0f);
  float var = ss * (1.0f / 1024.0f) - mu * mu;
  float inv = rsqrtf(var + 1e-5f);
  float4 g = *(const float4*)(sc + t * 4);
  float4 b = *(const float4*)(bi + t * 4);
  u16x4 o;
  o[0] = f2bf((v.x - mu) * inv * g.x + b.x);
  o[1] = f2bf((v.y - mu) * inv * g.y + b.y);
  o[2] = f2bf((v.z - mu) * inv * g.z + b.z);
  o[3] = f2bf((v.w - mu) * inv * g.w + b.w);
  *(u16x4*)(out + (size_t)row * 1024 + t * 4) = o;
}

// ---------------- transpose+convert: f32 src[R][C] -> bf16 dst[C][R] ----------------
__launch_bounds__(1024)
__global__ void k_transpose(const float* __restrict__ src, u16* __restrict__ dst,
                            int R, int C) {
  __shared__ float tile[32][33];
  int tx = threadIdx.x, ty = threadIdx.y;
  int c = blockIdx.x * 32 + tx;
  int r = blockIdx.y * 32 + ty;
  tile[ty][tx] = src[(size_t)r * C + c];
  __syncthreads();
  int dr = blockIdx.x * 32 + ty;   // dst row = src col
  int dc = blockIdx.y * 32 + tx;   // dst col = src row
  dst[(size_t)dr * R + dc] = f2bf(tile[tx][ty]);
}

// ---------------- GEMM 128x128 (2-phase): C = A x Bt^T ----------------
enum { EPI_QKV = 0, EPI_RES = 1, EPI_RELU = 2, EPI_OUT = 3 };

template <int EPI>
__launch_bounds__(256, 4)
__global__ void k_gemm(const u16* __restrict__ A, const u16* __restrict__ Bt,
                       const float* __restrict__ bias, float* __restrict__ fout,
                       u16* __restrict__ bout, int M, int N, int K) {
  __shared__ alignas(16) u16 sm[2][2][128][32];
  const int t = threadIdx.x;
  const int wave = t >> 6, lane = t & 63;
  const int wm = wave >> 1, wn = wave & 1;
  const int g = lane >> 4, c = lane & 15;
  const int m0 = blockIdx.x * 128, n0 = blockIdx.y * 128;

  const int srow = wave * 32 + (lane >> 2);
  const int sseg = (lane & 3) * 8;
  const u16* gA = A + (size_t)(m0 + srow) * K + sseg;
  const u16* gB = Bt + (size_t)(n0 + srow) * K + sseg;

  f32x4 acc[4][4] = {};

  const int nK = K >> 5;
  int cur = 0;

#pragma unroll
  for (int p = 0; p < 2; ++p) {
    GLOAD_LDS16(gA + (size_t)p * 16 * K, &sm[0][0][wave * 32 + p * 16][0]);
    GLOAD_LDS16(gB + (size_t)p * 16 * K, &sm[0][1][wave * 32 + p * 16][0]);
  }
  __syncthreads();

  for (int kt = 0; kt < nK; ++kt) {
    if (kt + 1 < nK) {
      const int k0 = (kt + 1) << 5;
#pragma unroll
      for (int p = 0; p < 2; ++p) {
        GLOAD_LDS16(gA + k0 + (size_t)p * 16 * K, &sm[cur ^ 1][0][wave * 32 + p * 16][0]);
        GLOAD_LDS16(gB + k0 + (size_t)p * 16 * K, &sm[cur ^ 1][1][wave * 32 + p * 16][0]);
      }
    }
    bf16x8 af[4], bfr[4];
#pragma unroll
    for (int i = 0; i < 4; ++i) {
      af[i]  = *(const bf16x8*)&sm[cur][0][wm * 64 + i * 16 + c][g * 8];
      bfr[i] = *(const bf16x8*)&sm[cur][1][wn * 64 + i * 16 + c][g * 8];
    }
#pragma unroll
    for (int i = 0; i < 4; ++i)
#pragma unroll
      for (int j = 0; j < 4; ++j)
        acc[i][j] = __builtin_amdgcn_mfma_f32_16x16x32_bf16(af[i], bfr[j], acc[i][j], 0, 0, 0);
    __syncthreads();
    cur ^= 1;
  }

#pragma unroll
  for (int i = 0; i < 4; ++i) {
#pragma unroll
    for (int j = 0; j < 4; ++j) {
#pragma unroll
      for (int r = 0; r < 4; ++r) {
        int m = m0 + wm * 64 + i * 16 + g * 4 + r;
        int n = n0 + wn * 64 + j * 16 + c;
        float v = acc[i][j][r];
        if (EPI == EPI_QKV) {
          int which = n >> 10;
          int hh = (n >> 6) & 15, f = n & 63;
          int b = m >> 10, tt = m & 1023;
          bout[(size_t)which * 2097152 +
               ((size_t)(b * 16 + hh) * 1024 + tt) * 64 + f] = f2bf(v);
        } else if (EPI == EPI_RES) {
          size_t off = (size_t)m * N + n;
          fout[off] += v + bias[n];
        } else if (EPI == EPI_RELU) {
          float u = v + bias[n];
          bout[(size_t)m * N + n] = f2bf(u > 0.f ? u : 0.f);
        }
      }
    }
  }
}

// ---------------- GEMM 256x256 8-phase (LM head, f32+bias out) ----------------
// BK=64, 8 waves (2Mx4N, interleaved halves), LDS 128KB double-buffered,
// T2 XOR-swizzle (pre-swizzled gload source + swizzled ds_read),
// counted vmcnt(4) at phases 4/8, raw s_barrier, setprio around MFMA.
// NOTE (rule #20): epilogue MUST be fully unrolled -> all acc indices static;
// runtime indexing spills the whole 128-reg acc to scratch (round-3 regression).

#define BARRIER_ASM asm volatile("s_barrier" ::: "memory")
#define VM4 asm volatile("s_waitcnt vmcnt(4)" ::: "memory")
#define VM0 asm volatile("s_waitcnt vmcnt(0)" ::: "memory")

#define STGA(sl, hf, kt)                                                       \
  {                                                                            \
    _Pragma("unroll") for (int p = 0; p < 2; ++p) {                            \
      int idx = p * 512 + t, rw = idx >> 3, sg = idx & 7;                      \
      GLOAD_LDS16(A + (size_t)(m0 + (hf)*128 + rw) * K + (kt)*64 +             \
                      ((sg ^ (rw & 7)) << 3),                                  \
                  &Alds[sl][(hf)*128 + rw][sg << 3]);                          \
    }                                                                          \
  }
#define STGB(sl, hf, kt)                                                       \
  {                                                                            \
    _Pragma("unroll") for (int p = 0; p < 2; ++p) {                            \
      int idx = p * 512 + t, rw = idx >> 3, sg = idx & 7;                      \
      GLOAD_LDS16(Bt + (size_t)(n0 + (hf)*128 + rw) * K + (kt)*64 +            \
                      ((sg ^ (rw & 7)) << 3),                                  \
                  &Blds[sl][(hf)*128 + rw][sg << 3]);                          \
    }                                                                          \
  }

#define PHASE(mh, nh, sl, STAGE_STMTS, VMWAIT)                                 \
  {                                                                            \
    bf16x8 af[4][2], bfm[2][2];                                                \
    _Pragma("unroll") for (int i = 0; i < 4; ++i) {                            \
      int ra = (mh)*128 + wm * 64 + i * 16 + c;                                \
      _Pragma("unroll") for (int ks = 0; ks < 2; ++ks)                         \
        af[i][ks] = *(const bf16x8*)&Alds[sl][ra][(((ks << 2) | g) ^ (ra & 7)) << 3]; \
    }                                                                          \
    _Pragma("unroll") for (int j = 0; j < 2; ++j) {                            \
      int rb = (nh)*128 + wn * 32 + j * 16 + c;                                \
      _Pragma("unroll") for (int ks = 0; ks < 2; ++ks)                         \
        bfm[j][ks] = *(const bf16x8*)&Blds[sl][rb][(((ks << 2) | g) ^ (rb & 7)) << 3]; \
    }                                                                          \
    STAGE_STMTS;                                                               \
    BARRIER_ASM;                                                               \
    __builtin_amdgcn_s_setprio(1);                                             \
    _Pragma("unroll") for (int i = 0; i < 4; ++i)                              \
      _Pragma("unroll") for (int j = 0; j < 2; ++j)                            \
        _Pragma("unroll") for (int ks = 0; ks < 2; ++ks)                       \
          acc[mh][nh][i][j] = __builtin_amdgcn_mfma_f32_16x16x32_bf16(         \
              af[i][ks], bfm[j][ks], acc[mh][nh][i][j], 0, 0, 0);              \
    __builtin_amdgcn_s_setprio(0);                                             \
    VMWAIT;                                                                    \
    BARRIER_ASM;                                                               \
  }

__launch_bounds__(512, 2)
__global__ void k_gemm_lm(const u16* __restrict__ A, const u16* __restrict__ Bt,
                          const float* __restrict__ bias, float* __restrict__ fout,
                          int M, int N, int K) {
  __shared__ alignas(16) u16 Alds[2][256][64];
  __shared__ alignas(16) u16 Blds[2][256][64];
  const int t = threadIdx.x;
  const int wid = t >> 6, lane = t & 63;
  const int wm = wid >> 2, wn = wid & 3;
  const int g = lane >> 4, c = lane & 15;

  // XCD-aware swizzle (nwg = 8*125 = 1000, 1000 % 8 == 0 -> simple bijection)
  int bid = blockIdx.x;
  int swz = (bid & 7) * 125 + (bid >> 3);
  const int m0 = (swz & 7) * 256, n0 = (swz >> 3) * 256;

  f32x4 acc[2][2][4][2] = {};

  const int nK = K >> 6;          // K-tiles of 64
  const int nIter = nK >> 1;      // 2 K-tiles per iteration

  // prologue: tile0 (slot0) all halves; tile1 (slot1) A-h0, B-h0
  STGA(0, 0, 0); STGB(0, 0, 0);
  STGA(0, 1, 0); STGB(0, 1, 0);
  STGA(1, 0, 1); STGB(1, 0, 1);
  VM4;            // tile0's 4 half-tiles (8 oldest loads) landed
  BARRIER_ASM;

  for (int it = 0; it < nIter; ++it) {
    const int t1 = 2 * it + 1, t2 = 2 * it + 2, t3 = 2 * it + 3;
    const bool more = (it + 1 < nIter);
    // phases 1-4: compute tile 2it (slot0)
    PHASE(0, 0, 0, { STGA(1, 1, t1); }, );
    PHASE(0, 1, 0, { STGB(1, 1, t1); }, );
    PHASE(1, 0, 0, { if (more) STGA(0, 0, t2); }, );
    if (more) { PHASE(1, 1, 0, { STGB(0, 0, t2); }, VM4); }
    else      { PHASE(1, 1, 0, { }, VM0); }
    // phases 5-8: compute tile 2it+1 (slot1)
    PHASE(0, 0, 1, { if (more) STGA(0, 1, t2); }, );
    PHASE(0, 1, 1, { if (more) STGB(0, 1, t2); }, );
    PHASE(1, 0, 1, { if (more) STGA(1, 0, t3); }, );
    if (more) { PHASE(1, 1, 1, { STGB(1, 0, t3); }, VM4); }
    else      { PHASE(1, 1, 1, { }, VM0); }
  }

  // epilogue: LDS-staged coalesced f32 stores, 8 chunks of 32 rows x 256 cols.
  // FULLY unrolled so acc indexing is compile-time static (rule #20).
  float (*stile)[260] = (float(*)[260])&Alds[0][0][0];  // 33.3KB, within Alds
#pragma unroll
  for (int RG = 0; RG < 8; ++RG) {
    const int mh = RG >> 2, wsel = (RG >> 1) & 1, ih = RG & 1;
    if (wm == wsel) {
#pragma unroll
      for (int i2 = 0; i2 < 2; ++i2)
#pragma unroll
        for (int nh = 0; nh < 2; ++nh)
#pragma unroll
          for (int j = 0; j < 2; ++j)
#pragma unroll
            for (int r = 0; r < 4; ++r) {
              float v = acc[mh][nh][ih * 2 + i2][j][r];
              stile[i2 * 16 + g * 4 + r][nh * 128 + wn * 32 + j * 16 + c] = v;
            }
    }
    __syncthreads();
    {
      int row = t >> 4, seg = t & 15;
      int m = m0 + RG * 32 + row;
      float* dst = fout + (size_t)m * N + n0 + seg * 16;
      const float* bsrc = bias + n0 + seg * 16;
#pragma unroll
      for (int q = 0; q < 4; ++q) {
        float4 v = *(const float4*)&stile[row][seg * 16 + q * 4];
        float4 bb = *(const float4*)&bsrc[q * 4];
        float4 o{v.x + bb.x, v.y + bb.y, v.z + bb.z, v.w + bb.w};
        *(float4*)(dst + q * 4) = o;
      }
    }
    __syncthreads();
  }
}

// ---------------- flash attention: 1 wave per (bh, 16 q-rows) ----------------
__launch_bounds__(64)
__global__ void k_attn(const u16* __restrict__ Q, const u16* __restrict__ Kb,
                       const u16* __restrict__ V, u16* __restrict__ O) {
  const int qb = blockIdx.x;       // 0..63
  const int bh = blockIdx.y;       // 0..31
  const int lane = threadIdx.x;
  const int g = lane >> 4, c = lane & 15;
  const int q0 = qb << 4;
  const u16* Qh = Q + (size_t)bh * 65536;
  const u16* Kh = Kb + (size_t)bh * 65536;
  const u16* Vh = V + (size_t)bh * 65536;

  __shared__ u16 Vt[64][40];
  __shared__ u16 Pl[16][40];

  const bf16x8 aq0 = *(const bf16x8*)(Qh + (q0 + c) * 64 + g * 8);
  const bf16x8 aq1 = *(const bf16x8*)(Qh + (q0 + c) * 64 + 32 + g * 8);

  f32x4 Oacc[4] = {};
  float Mr[4] = {-1e30f, -1e30f, -1e30f, -1e30f};
  float Lr[4] = {};

  const int nIt = (qb >> 1) + 1;
  for (int it = 0; it < nIt; ++it) {
    const int k0 = it << 5;
    f32x4 S0 = {}, S1 = {};
    {
      bf16x8 b0 = *(const bf16x8*)(Kh + (k0 + c) * 64 + g * 8);
      bf16x8 b1 = *(const bf16x8*)(Kh + (k0 + c) * 64 + 32 + g * 8);
      S0 = __builtin_amdgcn_mfma_f32_16x16x32_bf16(aq0, b0, S0, 0, 0, 0);
      S0 = __builtin_amdgcn_mfma_f32_16x16x32_bf16(aq1, b1, S0, 0, 0, 0);
      bf16x8 b2 = *(const bf16x8*)(Kh + (k0 + 16 + c) * 64 + g * 8);
      bf16x8 b3 = *(const bf16x8*)(Kh + (k0 + 16 + c) * 64 + 32 + g * 8);
      S1 = __builtin_amdgcn_mfma_f32_16x16x32_bf16(aq0, b2, S1, 0, 0, 0);
      S1 = __builtin_amdgcn_mfma_f32_16x16x32_bf16(aq1, b3, S1, 0, 0, 0);
    }
#pragma unroll
    for (int p = 0; p < 4; ++p) {
      int key = (p << 3) + (lane >> 3);
      int d0 = (lane & 7) << 3;
      u16x8 vv = *(const u16x8*)(Vh + (size_t)(k0 + key) * 64 + d0);
#pragma unroll
      for (int j = 0; j < 8; ++j) Vt[d0 + j][key] = vv[j];
    }
    const float scale = 0.125f;
#pragma unroll
    for (int r = 0; r < 4; ++r) {
      int q = q0 + (g << 2) + r;
      float s0 = (k0 + c <= q) ? S0[r] * scale : -1e30f;
      float s1 = (k0 + 16 + c <= q) ? S1[r] * scale : -1e30f;
      float m = fmaxf(s0, s1);
      m = fmaxf(m, __shfl_xor(m, 1));
      m = fmaxf(m, __shfl_xor(m, 2));
      m = fmaxf(m, __shfl_xor(m, 4));
      m = fmaxf(m, __shfl_xor(m, 8));
      float mnew = fmaxf(Mr[r], m);
      float p0 = expf(s0 - mnew);
      float p1 = expf(s1 - mnew);
      float rs = p0 + p1;
      rs += __shfl_xor(rs, 1);
      rs += __shfl_xor(rs, 2);
      rs += __shfl_xor(rs, 4);
      rs += __shfl_xor(rs, 8);
      float alpha = expf(Mr[r] - mnew);
      Lr[r] = Lr[r] * alpha + rs;
      Mr[r] = mnew;
#pragma unroll
      for (int nb = 0; nb < 4; ++nb) Oacc[nb][r] *= alpha;
      Pl[(g << 2) + r][c] = f2bf(p0);
      Pl[(g << 2) + r][16 + c] = f2bf(p1);
    }
    bf16x8 ap = *(const bf16x8*)&Pl[c][g * 8];
#pragma unroll
    for (int nb = 0; nb < 4; ++nb) {
      bf16x8 bv = *(const bf16x8*)&Vt[nb * 16 + c][g * 8];
      Oacc[nb] = __builtin_amdgcn_mfma_f32_16x16x32_bf16(ap, bv, Oacc[nb], 0, 0, 0);
    }
  }
  const int b = bh >> 4, hh = bh & 15;
#pragma unroll
  for (int r = 0; r < 4; ++r) {
    int tt = q0 + (g << 2) + r;
    float invl = 1.0f / Lr[r];
#pragma unroll
    for (int nb = 0; nb < 4; ++nb) {
      int d = nb * 16 + c;
      O[((size_t)(b * 1024 + tt)) * 1024 + hh * 64 + d] = f2bf(Oacc[nb][r] * invl);
    }
  }
}

// ---------------- launch ----------------
extern "C" void kernel_launch(void* const* d_in, const int* in_sizes, int n_in,
                              void* d_out, int out_size, void* d_ws, size_t ws_size,
                              hipStream_t stream) {
  const int*   idx  = (const int*)d_in[0];
  const float* tok  = (const float*)d_in[1];
  const float* pos  = (const float*)d_in[2];
  const float* Wq   = (const float*)d_in[3];
  const float* Wk   = (const float*)d_in[4];
  const float* Wv   = (const float*)d_in[5];
  const float* Wo   = (const float*)d_in[6];
  const float* bo   = (const float*)d_in[7];
  const float* ln1s = (const float*)d_in[8];
  const float* ln1b = (const float*)d_in[9];
  const float* ln2s = (const float*)d_in[10];
  const float* ln2b = (const float*)d_in[11];
  const float* W1   = (const float*)d_in[12];
  const float* b1   = (const float*)d_in[13];
  const float* W2   = (const float*)d_in[14];
  const float* b2   = (const float*)d_in[15];
  const float* lnfs = (const float*)d_in[16];
  const float* lnfb = (const float*)d_in[17];
  const float* Wlm  = (const float*)d_in[18];
  const float* blm  = (const float*)d_in[19];
  float* out = (float*)d_out;

  char* w = (char*)d_ws;
  auto alloc = [&](size_t bytes) {
    char* p = w;
    w += (bytes + 255) & ~(size_t)255;
    return p;
  };
  float* x  = (float*)alloc(2048ull * 1024 * 4);
  u16* h    = (u16*)alloc(2048ull * 1024 * 2);
  u16* qkv  = (u16*)alloc(3ull * 2097152 * 2);
  u16* o    = (u16*)alloc(2048ull * 1024 * 2);
  u16* a1   = (u16*)alloc(2048ull * 4096 * 2);
  u16* arena = (u16*)alloc(32000ull * 1024 * 2);

  dim3 b32(32, 32, 1);

  k_embed<<<2048, 256, 0, stream>>>(idx, tok, pos, x);

  for (int l = 0; l < 4; ++l) {
    u16* qkvT = arena;
    u16* WoT  = arena + 3ull * 1048576;
    u16* W1T  = arena + 4ull * 1048576;
    u16* W2T  = arena + 8ull * 1048576;
    k_transpose<<<dim3(32, 32), b32, 0, stream>>>(Wq + (size_t)l * 1048576, qkvT,            1024, 1024);
    k_transpose<<<dim3(32, 32), b32, 0, stream>>>(Wk + (size_t)l * 1048576, qkvT + 1048576,  1024, 1024);
    k_transpose<<<dim3(32, 32), b32, 0, stream>>>(Wv + (size_t)l * 1048576, qkvT + 2097152,  1024, 1024);
    k_transpose<<<dim3(32, 32), b32, 0, stream>>>(Wo + (size_t)l * 1048576, WoT, 1024, 1024);
    k_transpose<<<dim3(128, 32), b32, 0, stream>>>(W1 + (size_t)l * 4194304, W1T, 1024, 4096);
    k_transpose<<<dim3(32, 128), b32, 0, stream>>>(W2 + (size_t)l * 4194304, W2T, 4096, 1024);

    k_ln<<<2048, 256, 0, stream>>>(x, ln1s + l * 1024, ln1b + l * 1024, h);
    k_gemm<EPI_QKV><<<dim3(16, 24), 256, 0, stream>>>(h, qkvT, nullptr, nullptr, qkv,
                                                      2048, 3072, 1024);
    k_attn<<<dim3(64, 32), 64, 0, stream>>>(qkv, qkv + 2097152, qkv + 2 * 2097152, o);
    k_gemm<EPI_RES><<<dim3(16, 8), 256, 0, stream>>>(o, WoT, bo + l * 1024, x, nullptr,
                                                     2048, 1024, 1024);
    k_ln<<<2048, 256, 0, stream>>>(x, ln2s + l * 1024, ln2b + l * 1024, h);
    k_gemm<EPI_RELU><<<dim3(16, 32), 256, 0, stream>>>(h, W1T, b1 + l * 4096, nullptr, a1,
                                                       2048, 4096, 1024);
    k_gemm<EPI_RES><<<dim3(16, 8), 256, 0, stream>>>(a1, W2T, b2 + l * 1024, x, nullptr,
                                                     2048, 1024, 4096);
  }

  k_ln<<<2048, 256, 0, stream>>>(x, lnfs, lnfb, h);
  k_transpose<<<dim3(1000, 32), b32, 0, stream>>>(Wlm, arena, 1024, 32000);
  k_gemm_lm<<<1000, 512, 0, stream>>>(h, arena, blm, out, 2048, 32000, 1024);
}

// Round 5
// 1391.523 us; speedup vs baseline: 1.6738x; 1.0808x over previous
//
#include <hip/hip_runtime.h>

typedef unsigned short u16;
typedef unsigned int u32;
typedef __bf16 bf16x8 __attribute__((ext_vector_type(8)));
typedef float f32x4 __attribute__((ext_vector_type(4)));
typedef u16 u16x8 __attribute__((ext_vector_type(8)));
typedef u16 u16x4 __attribute__((ext_vector_type(4)));

static __device__ __forceinline__ u16 f2bf(float f) {
  u32 u = __builtin_bit_cast(u32, f);
  u32 r = (u + 0x7FFFu + ((u >> 16) & 1u)) >> 16;  // RNE; inputs finite
  return (u16)r;
}

#define GLOAD_LDS16(gp, lp)                                                   \
  __builtin_amdgcn_global_load_lds(                                           \
      (const __attribute__((address_space(1))) void*)(gp),                    \
      (__attribute__((address_space(3))) void*)(lp), 16, 0, 0)

// ---------------- embedding: x = tok_emb[idx] + pos_emb ----------------
__global__ void k_embed(const int* __restrict__ idx, const float* __restrict__ tok,
                        const float* __restrict__ pos, float* __restrict__ x) {
  int row = blockIdx.x;            // b*1024 + t
  int t = row & 1023;
  int id = idx[row];
  int c = threadIdx.x * 4;
  float4 a = *(const float4*)(tok + (size_t)id * 1024 + c);
  float4 p = *(const float4*)(pos + (size_t)t * 1024 + c);
  float4 r{a.x + p.x, a.y + p.y, a.z + p.z, a.w + p.w};
  *(float4*)(x + (size_t)row * 1024 + c) = r;
}

// ---------------- layernorm (f32 in) -> bf16 out ----------------
__global__ void k_ln(const float* __restrict__ x, const float* __restrict__ sc,
                     const float* __restrict__ bi, u16* __restrict__ out) {
  int row = blockIdx.x;
  int t = threadIdx.x;
  const float* xr = x + (size_t)row * 1024;
  float4 v = *(const float4*)(xr + t * 4);
  float s = v.x + v.y + v.z + v.w;
  float ss = v.x * v.x + v.y * v.y + v.z * v.z + v.w * v.w;
  for (int d = 1; d < 64; d <<= 1) { s += __shfl_xor(s, d); ss += __shfl_xor(ss, d); }
  __shared__ float red[8];
  int wave = t >> 6, lane = t & 63;
  if (lane == 0) { red[wave] = s; red[wave + 4] = ss; }
  __syncthreads();
  s = red[0] + red[1] + red[2] + red[3];
  ss = red[4] + red[5] + red[6] + red[7];
  float mu = s * (1.0f / 1024.0f);
  float var = ss * (1.0f / 1024.0f) - mu * mu;
  float inv = rsqrtf(var + 1e-5f);
  float4 g = *(const float4*)(sc + t * 4);
  float4 b = *(const float4*)(bi + t * 4);
  u16x4 o;
  o[0] = f2bf((v.x - mu) * inv * g.x + b.x);
  o[1] = f2bf((v.y - mu) * inv * g.y + b.y);
  o[2] = f2bf((v.z - mu) * inv * g.z + b.z);
  o[3] = f2bf((v.w - mu) * inv * g.w + b.w);
  *(u16x4*)(out + (size_t)row * 1024 + t * 4) = o;
}

// ---------------- transpose+convert: f32 src[R][C] -> bf16 dst[C][R] ----------------
__launch_bounds__(1024)
__global__ void k_transpose(const float* __restrict__ src, u16* __restrict__ dst,
                            int R, int C) {
  __shared__ float tile[32][33];
  int tx = threadIdx.x, ty = threadIdx.y;
  int c = blockIdx.x * 32 + tx;
  int r = blockIdx.y * 32 + ty;
  tile[ty][tx] = src[(size_t)r * C + c];
  __syncthreads();
  int dr = blockIdx.x * 32 + ty;
  int dc = blockIdx.y * 32 + tx;
  dst[(size_t)dr * R + dc] = f2bf(tile[tx][ty]);
}

// ---------------- fused per-layer weight transpose (6 matrices, 1 launch) ----------
__launch_bounds__(1024)
__global__ void k_transpose_layer(const float* __restrict__ Wq, const float* __restrict__ Wk,
                                  const float* __restrict__ Wv, const float* __restrict__ Wo,
                                  const float* __restrict__ W1, const float* __restrict__ W2,
                                  u16* __restrict__ qkvT, u16* __restrict__ WoT,
                                  u16* __restrict__ W1T, u16* __restrict__ W2T) {
  int bid = blockIdx.x;
  const float* src; u16* dst; int R, C, bx, by;
  if (bid < 4096) {
    int which = bid >> 10, tile_i = bid & 1023;
    bx = tile_i & 31; by = tile_i >> 5; R = 1024; C = 1024;
    src = which == 0 ? Wq : which == 1 ? Wk : which == 2 ? Wv : Wo;
    dst = which == 3 ? WoT : qkvT + (size_t)which * 1048576;
  } else if (bid < 8192) {
    int tile_i = bid - 4096; bx = tile_i & 127; by = tile_i >> 7; R = 1024; C = 4096;
    src = W1; dst = W1T;
  } else {
    int tile_i = bid - 8192; bx = tile_i & 31; by = tile_i >> 5; R = 4096; C = 1024;
    src = W2; dst = W2T;
  }
  __shared__ float tile[32][33];
  int tx = threadIdx.x, ty = threadIdx.y;
  int c = bx * 32 + tx, r = by * 32 + ty;
  tile[ty][tx] = src[(size_t)r * C + c];
  __syncthreads();
  int dr = bx * 32 + ty, dc = by * 32 + tx;
  dst[(size_t)dr * R + dc] = f2bf(tile[tx][ty]);
}

// ---------------- GEMMs: C[M][N] = A[M][K](bf16) x Bt[N][K](bf16)^T ----------------
enum { EPI_QKV = 0, EPI_RES = 1, EPI_RELU = 2 };

// 128x128 tile, 2-phase pipelined (for RELU gemm: 512 blocks)
template <int EPI>
__launch_bounds__(256, 4)
__global__ void k_gemm(const u16* __restrict__ A, const u16* __restrict__ Bt,
                       const float* __restrict__ bias, float* __restrict__ fout,
                       u16* __restrict__ bout, int M, int N, int K) {
  __shared__ alignas(16) u16 sm[2][2][128][32];
  const int t = threadIdx.x;
  const int wave = t >> 6, lane = t & 63;
  const int wm = wave >> 1, wn = wave & 1;
  const int g = lane >> 4, c = lane & 15;
  const int m0 = blockIdx.x * 128, n0 = blockIdx.y * 128;

  const int srow = wave * 32 + (lane >> 2);
  const int sseg = (lane & 3) * 8;
  const u16* gA = A + (size_t)(m0 + srow) * K + sseg;
  const u16* gB = Bt + (size_t)(n0 + srow) * K + sseg;

  f32x4 acc[4][4] = {};
  const int nK = K >> 5;
  int cur = 0;

#pragma unroll
  for (int p = 0; p < 2; ++p) {
    GLOAD_LDS16(gA + (size_t)p * 16 * K, &sm[0][0][wave * 32 + p * 16][0]);
    GLOAD_LDS16(gB + (size_t)p * 16 * K, &sm[0][1][wave * 32 + p * 16][0]);
  }
  __syncthreads();

  for (int kt = 0; kt < nK; ++kt) {
    if (kt + 1 < nK) {
      const int k0 = (kt + 1) << 5;
#pragma unroll
      for (int p = 0; p < 2; ++p) {
        GLOAD_LDS16(gA + k0 + (size_t)p * 16 * K, &sm[cur ^ 1][0][wave * 32 + p * 16][0]);
        GLOAD_LDS16(gB + k0 + (size_t)p * 16 * K, &sm[cur ^ 1][1][wave * 32 + p * 16][0]);
      }
    }
    bf16x8 af[4], bfr[4];
#pragma unroll
    for (int i = 0; i < 4; ++i) {
      af[i]  = *(const bf16x8*)&sm[cur][0][wm * 64 + i * 16 + c][g * 8];
      bfr[i] = *(const bf16x8*)&sm[cur][1][wn * 64 + i * 16 + c][g * 8];
    }
#pragma unroll
    for (int i = 0; i < 4; ++i)
#pragma unroll
      for (int j = 0; j < 4; ++j)
        acc[i][j] = __builtin_amdgcn_mfma_f32_16x16x32_bf16(af[i], bfr[j], acc[i][j], 0, 0, 0);
    __syncthreads();
    cur ^= 1;
  }

#pragma unroll
  for (int i = 0; i < 4; ++i)
#pragma unroll
    for (int j = 0; j < 4; ++j)
#pragma unroll
      for (int r = 0; r < 4; ++r) {
        int m = m0 + wm * 64 + i * 16 + g * 4 + r;
        int n = n0 + wn * 64 + j * 16 + c;
        float v = acc[i][j][r];
        if (EPI == EPI_QKV) {
          int which = n >> 10;
          int hh = (n >> 6) & 15, f = n & 63;
          int b = m >> 10, tt = m & 1023;
          bout[(size_t)which * 2097152 +
               ((size_t)(b * 16 + hh) * 1024 + tt) * 64 + f] = f2bf(v);
        } else if (EPI == EPI_RES) {
          fout[(size_t)m * N + n] += v + bias[n];
        } else if (EPI == EPI_RELU) {
          float u = v + bias[n];
          bout[(size_t)m * N + n] = f2bf(u > 0.f ? u : 0.f);
        }
      }
}

// 64x128 tile, 2-phase pipelined (QKV / residual gemms: full-GPU grids)
template <int EPI>
__launch_bounds__(256, 4)
__global__ void k_gemm64(const u16* __restrict__ A, const u16* __restrict__ Bt,
                         const float* __restrict__ bias, float* __restrict__ fout,
                         u16* __restrict__ bout, int M, int N, int K) {
  __shared__ alignas(16) u16 Al[2][64][32];
  __shared__ alignas(16) u16 Bl[2][128][32];
  const int t = threadIdx.x;
  const int wave = t >> 6, lane = t & 63;
  const int wm = wave >> 1, wn = wave & 1;       // 2x2 waves: 32x64 out each
  const int g = lane >> 4, c = lane & 15;
  const int m0 = blockIdx.x * 64, n0 = blockIdx.y * 128;

  const int rwA = t >> 2, sgA = (t & 3) * 8;     // A: 64 rows, 1 instr
  const u16* gA = A + (size_t)(m0 + rwA) * K + sgA;
  const int rwB = t >> 2, sgB = sgA;             // B: 128 rows, 2 instrs
  const u16* gB = Bt + (size_t)(n0 + rwB) * K + sgB;

  f32x4 acc[2][4] = {};
  const int nK = K >> 5;
  int cur = 0;

  GLOAD_LDS16(gA, &Al[0][rwA][0]);
#pragma unroll
  for (int p = 0; p < 2; ++p)
    GLOAD_LDS16(gB + (size_t)p * 64 * K, &Bl[0][p * 64 + rwB][0]);
  __syncthreads();

  for (int kt = 0; kt < nK; ++kt) {
    if (kt + 1 < nK) {
      const int k0 = (kt + 1) << 5;
      GLOAD_LDS16(gA + k0, &Al[cur ^ 1][rwA][0]);
#pragma unroll
      for (int p = 0; p < 2; ++p)
        GLOAD_LDS16(gB + k0 + (size_t)p * 64 * K, &Bl[cur ^ 1][p * 64 + rwB][0]);
    }
    bf16x8 af[2], bfr[4];
#pragma unroll
    for (int i = 0; i < 2; ++i)
      af[i] = *(const bf16x8*)&Al[cur][wm * 32 + i * 16 + c][g * 8];
#pragma unroll
    for (int j = 0; j < 4; ++j)
      bfr[j] = *(const bf16x8*)&Bl[cur][wn * 64 + j * 16 + c][g * 8];
#pragma unroll
    for (int i = 0; i < 2; ++i)
#pragma unroll
      for (int j = 0; j < 4; ++j)
        acc[i][j] = __builtin_amdgcn_mfma_f32_16x16x32_bf16(af[i], bfr[j], acc[i][j], 0, 0, 0);
    __syncthreads();
    cur ^= 1;
  }

#pragma unroll
  for (int i = 0; i < 2; ++i)
#pragma unroll
    for (int j = 0; j < 4; ++j)
#pragma unroll
      for (int r = 0; r < 4; ++r) {
        int m = m0 + wm * 32 + i * 16 + g * 4 + r;
        int n = n0 + wn * 64 + j * 16 + c;
        float v = acc[i][j][r];
        if (EPI == EPI_QKV) {
          int which = n >> 10;
          int hh = (n >> 6) & 15, f = n & 63;
          int b = m >> 10, tt = m & 1023;
          bout[(size_t)which * 2097152 +
               ((size_t)(b * 16 + hh) * 1024 + tt) * 64 + f] = f2bf(v);
        } else if (EPI == EPI_RES) {
          fout[(size_t)m * N + n] += v + bias[n];
        }
      }
}

// ---------------- GEMM 256x256 8-phase (LM head, f32+bias out) ----------------
// Quadrant order (0,0)(0,1)(1,1)(1,0) with persistent af/bf0/bf1 frag registers:
// ds_reads per slot-group 48 -> 20 (m201 pattern). Rule #20: all acc indices static.

#define BARRIER_ASM asm volatile("s_barrier" ::: "memory")
#define VM4 asm volatile("s_waitcnt vmcnt(4)" ::: "memory")
#define VM0 asm volatile("s_waitcnt vmcnt(0)" ::: "memory")

#define STGA(sl, hf, kt)                                                       \
  {                                                                            \
    _Pragma("unroll") for (int p = 0; p < 2; ++p) {                            \
      int idx = p * 512 + t, rw = idx >> 3, sg = idx & 7;                      \
      GLOAD_LDS16(A + (size_t)(m0 + (hf)*128 + rw) * K + (kt)*64 +             \
                      ((sg ^ (rw & 7)) << 3),                                  \
                  &Alds[sl][(hf)*128 + rw][sg << 3]);                          \
    }                                                                          \
  }
#define STGB(sl, hf, kt)                                                       \
  {                                                                            \
    _Pragma("unroll") for (int p = 0; p < 2; ++p) {                            \
      int idx = p * 512 + t, rw = idx >> 3, sg = idx & 7;                      \
      GLOAD_LDS16(Bt + (size_t)(n0 + (hf)*128 + rw) * K + (kt)*64 +            \
                      ((sg ^ (rw & 7)) << 3),                                  \
                  &Blds[sl][(hf)*128 + rw][sg << 3]);                          \
    }                                                                          \
  }

#define LMLOAD_A(sl, mh)                                                       \
  _Pragma("unroll") for (int i = 0; i < 4; ++i) {                              \
    int ra = (mh)*128 + wm * 64 + i * 16 + c;                                  \
    _Pragma("unroll") for (int ks = 0; ks < 2; ++ks)                           \
      af[i][ks] = *(const bf16x8*)&Alds[sl][ra][(((ks << 2) | g) ^ (ra & 7)) << 3]; \
  }
#define LMLOAD_B(sl, nh, bfv)                                                  \
  _Pragma("unroll") for (int j = 0; j < 2; ++j) {                              \
    int rb = (nh)*128 + wn * 32 + j * 16 + c;                                  \
    _Pragma("unroll") for (int ks = 0; ks < 2; ++ks)                           \
      bfv[j][ks] = *(const bf16x8*)&Blds[sl][rb][(((ks << 2) | g) ^ (rb & 7)) << 3]; \
  }
#define LMMMA(mh, nh, bfv)                                                     \
  __builtin_amdgcn_s_setprio(1);                                               \
  _Pragma("unroll") for (int i = 0; i < 4; ++i)                                \
    _Pragma("unroll") for (int j = 0; j < 2; ++j)                              \
      _Pragma("unroll") for (int ks = 0; ks < 2; ++ks)                         \
        acc[mh][nh][i][j] = __builtin_amdgcn_mfma_f32_16x16x32_bf16(           \
            af[i][ks], bfv[j][ks], acc[mh][nh][i][j], 0, 0, 0);                \
  __builtin_amdgcn_s_setprio(0);

__launch_bounds__(512, 2)
__global__ void k_gemm_lm(const u16* __restrict__ A, const u16* __restrict__ Bt,
                          const float* __restrict__ bias, float* __restrict__ fout,
                          int M, int N, int K) {
  __shared__ alignas(16) u16 Alds[2][256][64];
  __shared__ alignas(16) u16 Blds[2][256][64];
  const int t = threadIdx.x;
  const int wid = t >> 6, lane = t & 63;
  const int wm = wid >> 2, wn = wid & 3;
  const int g = lane >> 4, c = lane & 15;

  // XCD-aware: same-XCD consecutive blocks share a B-panel (L2 reuse)
  int bid = blockIdx.x;
  int swz = (bid & 7) * 125 + (bid >> 3);
  const int m0 = (swz & 7) * 256, n0 = (swz >> 3) * 256;

  f32x4 acc[2][2][4][2] = {};
  bf16x8 af[4][2], bf0[2][2], bf1[2][2];

  const int nK = K >> 6;
  const int nIter = nK >> 1;

  STGA(0, 0, 0); STGB(0, 0, 0);
  STGA(0, 1, 0); STGB(0, 1, 0);
  STGA(1, 0, 1); STGB(1, 0, 1);
  VM4;
  BARRIER_ASM;

  for (int it = 0; it < nIter; ++it) {
    const int t1 = 2 * it + 1, t2 = 2 * it + 2, t3 = 2 * it + 3;
    const bool more = (it + 1 < nIter);
    // ---- slot 0 = tile 2it: (0,0)(0,1)(1,1)(1,0) ----
    LMLOAD_A(0, 0); LMLOAD_B(0, 0, bf0);
    STGA(1, 1, t1);
    BARRIER_ASM; LMMMA(0, 0, bf0); BARRIER_ASM;
    LMLOAD_B(0, 1, bf1);
    STGB(1, 1, t1);
    BARRIER_ASM; LMMMA(0, 1, bf1); BARRIER_ASM;
    LMLOAD_A(0, 1);
    if (more) { STGA(0, 0, t2); }
    BARRIER_ASM; LMMMA(1, 1, bf1); BARRIER_ASM;
    if (more) { STGB(0, 0, t2); BARRIER_ASM; LMMMA(1, 0, bf0); VM4; BARRIER_ASM; }
    else      { BARRIER_ASM; LMMMA(1, 0, bf0); VM0; BARRIER_ASM; }
    // ---- slot 1 = tile 2it+1 ----
    LMLOAD_A(1, 0); LMLOAD_B(1, 0, bf0);
    if (more) { STGA(0, 1, t2); }
    BARRIER_ASM; LMMMA(0, 0, bf0); BARRIER_ASM;
    LMLOAD_B(1, 1, bf1);
    if (more) { STGB(0, 1, t2); }
    BARRIER_ASM; LMMMA(0, 1, bf1); BARRIER_ASM;
    LMLOAD_A(1, 1);
    if (more) { STGA(1, 0, t3); }
    BARRIER_ASM; LMMMA(1, 1, bf1); BARRIER_ASM;
    if (more) { STGB(1, 0, t3); BARRIER_ASM; LMMMA(1, 0, bf0); VM4; BARRIER_ASM; }
    else      { BARRIER_ASM; LMMMA(1, 0, bf0); VM0; BARRIER_ASM; }
  }

  // epilogue: LDS-staged coalesced f32 stores; fully unrolled (static acc idx)
  float (*stile)[260] = (float(*)[260])&Alds[0][0][0];
#pragma unroll
  for (int RG = 0; RG < 8; ++RG) {
    const int mh = RG >> 2, wsel = (RG >> 1) & 1, ih = RG & 1;
    if (wm == wsel) {
#pragma unroll
      for (int i2 = 0; i2 < 2; ++i2)
#pragma unroll
        for (int nh = 0; nh < 2; ++nh)
#pragma unroll
          for (int j = 0; j < 2; ++j)
#pragma unroll
            for (int r = 0; r < 4; ++r) {
              float v = acc[mh][nh][ih * 2 + i2][j][r];
              stile[i2 * 16 + g * 4 + r][nh * 128 + wn * 32 + j * 16 + c] = v;
            }
    }
    __syncthreads();
    {
      int row = t >> 4, seg = t & 15;
      int m = m0 + RG * 32 + row;
      float* dst = fout + (size_t)m * N + n0 + seg * 16;
      const float* bsrc = bias + n0 + seg * 16;
#pragma unroll
      for (int q = 0; q < 4; ++q) {
        float4 v = *(const float4*)&stile[row][seg * 16 + q * 4];
        float4 bb = *(const float4*)&bsrc[q * 4];
        float4 o{v.x + bb.x, v.y + bb.y, v.z + bb.z, v.w + bb.w};
        *(float4*)(dst + q * 4) = o;
      }
    }
    __syncthreads();
  }
}

// ---------------- flash attention: 1 wave per (bh, 16 q-rows) ----------------
__launch_bounds__(64)
__global__ void k_attn(const u16* __restrict__ Q, const u16* __restrict__ Kb,
                       const u16* __restrict__ V, u16* __restrict__ O) {
  const int qb = blockIdx.x;
  const int bh = blockIdx.y;
  const int lane = threadIdx.x;
  const int g = lane >> 4, c = lane & 15;
  const int q0 = qb << 4;
  const u16* Qh = Q + (size_t)bh * 65536;
  const u16* Kh = Kb + (size_t)bh * 65536;
  const u16* Vh = V + (size_t)bh * 65536;

  __shared__ u16 Vt[64][40];
  __shared__ u16 Pl[16][40];

  const bf16x8 aq0 = *(const bf16x8*)(Qh + (q0 + c) * 64 + g * 8);
  const bf16x8 aq1 = *(const bf16x8*)(Qh + (q0 + c) * 64 + 32 + g * 8);

  f32x4 Oacc[4] = {};
  float Mr[4] = {-1e30f, -1e30f, -1e30f, -1e30f};
  float Lr[4] = {};

  const int nIt = (qb >> 1) + 1;
  for (int it = 0; it < nIt; ++it) {
    const int k0 = it << 5;
    f32x4 S0 = {}, S1 = {};
    {
      bf16x8 b0 = *(const bf16x8*)(Kh + (k0 + c) * 64 + g * 8);
      bf16x8 b1 = *(const bf16x8*)(Kh + (k0 + c) * 64 + 32 + g * 8);
      S0 = __builtin_amdgcn_mfma_f32_16x16x32_bf16(aq0, b0, S0, 0, 0, 0);
      S0 = __builtin_amdgcn_mfma_f32_16x16x32_bf16(aq1, b1, S0, 0, 0, 0);
      bf16x8 b2 = *(const bf16x8*)(Kh + (k0 + 16 + c) * 64 + g * 8);
      bf16x8 b3 = *(const bf16x8*)(Kh + (k0 + 16 + c) * 64 + 32 + g * 8);
      S1 = __builtin_amdgcn_mfma_f32_16x16x32_bf16(aq0, b2, S1, 0, 0, 0);
      S1 = __builtin_amdgcn_mfma_f32_16x16x32_bf16(aq1, b3, S1, 0, 0, 0);
    }
#pragma unroll
    for (int p = 0; p < 4; ++p) {
      int key = (p << 3) + (lane >> 3);
      int d0 = (lane & 7) << 3;
      u16x8 vv = *(const u16x8*)(Vh + (size_t)(k0 + key) * 64 + d0);
#pragma unroll
      for (int j = 0; j < 8; ++j) Vt[d0 + j][key] = vv[j];
    }
    const float scale = 0.125f;
#pragma unroll
    for (int r = 0; r < 4; ++r) {
      int q = q0 + (g << 2) + r;
      float s0 = (k0 + c <= q) ? S0[r] * scale : -1e30f;
      float s1 = (k0 + 16 + c <= q) ? S1[r] * scale : -1e30f;
      float m = fmaxf(s0, s1);
      m = fmaxf(m, __shfl_xor(m, 1));
      m = fmaxf(m, __shfl_xor(m, 2));
      m = fmaxf(m, __shfl_xor(m, 4));
      m = fmaxf(m, __shfl_xor(m, 8));
      float mnew = fmaxf(Mr[r], m);
      float p0 = __expf(s0 - mnew);
      float p1 = __expf(s1 - mnew);
      float rs = p0 + p1;
      rs += __shfl_xor(rs, 1);
      rs += __shfl_xor(rs, 2);
      rs += __shfl_xor(rs, 4);
      rs += __shfl_xor(rs, 8);
      float alpha = __expf(Mr[r] - mnew);
      Lr[r] = Lr[r] * alpha + rs;
      Mr[r] = mnew;
#pragma unroll
      for (int nb = 0; nb < 4; ++nb) Oacc[nb][r] *= alpha;
      Pl[(g << 2) + r][c] = f2bf(p0);
      Pl[(g << 2) + r][16 + c] = f2bf(p1);
    }
    bf16x8 ap = *(const bf16x8*)&Pl[c][g * 8];
#pragma unroll
    for (int nb = 0; nb < 4; ++nb) {
      bf16x8 bv = *(const bf16x8*)&Vt[nb * 16 + c][g * 8];
      Oacc[nb] = __builtin_amdgcn_mfma_f32_16x16x32_bf16(ap, bv, Oacc[nb], 0, 0, 0);
    }
  }
  const int b = bh >> 4, hh = bh & 15;
#pragma unroll
  for (int r = 0; r < 4; ++r) {
    int tt = q0 + (g << 2) + r;
    float invl = 1.0f / Lr[r];
#pragma unroll
    for (int nb = 0; nb < 4; ++nb) {
      int d = nb * 16 + c;
      O[((size_t)(b * 1024 + tt)) * 1024 + hh * 64 + d] = f2bf(Oacc[nb][r] * invl);
    }
  }
}

// ---------------- launch ----------------
extern "C" void kernel_launch(void* const* d_in, const int* in_sizes, int n_in,
                              void* d_out, int out_size, void* d_ws, size_t ws_size,
                              hipStream_t stream) {
  const int*   idx  = (const int*)d_in[0];
  const float* tok  = (const float*)d_in[1];
  const float* pos  = (const float*)d_in[2];
  const float* Wq   = (const float*)d_in[3];
  const float* Wk   = (const float*)d_in[4];
  const float* Wv   = (const float*)d_in[5];
  const float* Wo   = (const float*)d_in[6];
  const float* bo   = (const float*)d_in[7];
  const float* ln1s = (const float*)d_in[8];
  const float* ln1b = (const float*)d_in[9];
  const float* ln2s = (const float*)d_in[10];
  const float* ln2b = (const float*)d_in[11];
  const float* W1   = (const float*)d_in[12];
  const float* b1   = (const float*)d_in[13];
  const float* W2   = (const float*)d_in[14];
  const float* b2   = (const float*)d_in[15];
  const float* lnfs = (const float*)d_in[16];
  const float* lnfb = (const float*)d_in[17];
  const float* Wlm  = (const float*)d_in[18];
  const float* blm  = (const float*)d_in[19];
  float* out = (float*)d_out;

  char* w = (char*)d_ws;
  auto alloc = [&](size_t bytes) {
    char* p = w;
    w += (bytes + 255) & ~(size_t)255;
    return p;
  };
  float* x  = (float*)alloc(2048ull * 1024 * 4);
  u16* h    = (u16*)alloc(2048ull * 1024 * 2);
  u16* qkv  = (u16*)alloc(3ull * 2097152 * 2);
  u16* o    = (u16*)alloc(2048ull * 1024 * 2);
  u16* a1   = (u16*)alloc(2048ull * 4096 * 2);
  u16* arena = (u16*)alloc(32000ull * 1024 * 2);

  dim3 b32(32, 32, 1);

  k_embed<<<2048, 256, 0, stream>>>(idx, tok, pos, x);

  for (int l = 0; l < 4; ++l) {
    u16* qkvT = arena;
    u16* WoT  = arena + 3ull * 1048576;
    u16* W1T  = arena + 4ull * 1048576;
    u16* W2T  = arena + 8ull * 1048576;
    k_transpose_layer<<<12288, b32, 0, stream>>>(
        Wq + (size_t)l * 1048576, Wk + (size_t)l * 1048576,
        Wv + (size_t)l * 1048576, Wo + (size_t)l * 1048576,
        W1 + (size_t)l * 4194304, W2 + (size_t)l * 4194304,
        qkvT, WoT, W1T, W2T);

    k_ln<<<2048, 256, 0, stream>>>(x, ln1s + l * 1024, ln1b + l * 1024, h);
    k_gemm64<EPI_QKV><<<dim3(32, 24), 256, 0, stream>>>(h, qkvT, nullptr, nullptr, qkv,
                                                        2048, 3072, 1024);
    k_attn<<<dim3(64, 32), 64, 0, stream>>>(qkv, qkv + 2097152, qkv + 2 * 2097152, o);
    k_gemm64<EPI_RES><<<dim3(32, 8), 256, 0, stream>>>(o, WoT, bo + l * 1024, x, nullptr,
                                                       2048, 1024, 1024);
    k_ln<<<2048, 256, 0, stream>>>(x, ln2s + l * 1024, ln2b + l * 1024, h);
    k_gemm<EPI_RELU><<<dim3(16, 32), 256, 0, stream>>>(h, W1T, b1 + l * 4096, nullptr, a1,
                                                       2048, 4096, 1024);
    k_gemm64<EPI_RES><<<dim3(32, 8), 256, 0, stream>>>(a1, W2T, b2 + l * 1024, x, nullptr,
                                                       2048, 1024, 4096);
  }

  k_ln<<<2048, 256, 0, stream>>>(x, lnfs, lnfb, h);
  k_transpose<<<dim3(1000, 32), b32, 0, stream>>>(Wlm, arena, 1024, 32000);
  k_gemm_lm<<<1000, 512, 0, stream>>>(h, arena, blm, out, 2048, 32000, 1024);
}

// Round 6
// 1270.235 us; speedup vs baseline: 1.8336x; 1.0955x over previous
//
#include <hip/hip_runtime.h>

typedef unsigned short u16;
typedef unsigned int u32;
typedef __bf16 bf16x8 __attribute__((ext_vector_type(8)));
typedef float f32x4 __attribute__((ext_vector_type(4)));
typedef u16 u16x8 __attribute__((ext_vector_type(8)));
typedef u16 u16x4 __attribute__((ext_vector_type(4)));

static __device__ __forceinline__ u16 f2bf(float f) {
  u32 u = __builtin_bit_cast(u32, f);
  u32 r = (u + 0x7FFFu + ((u >> 16) & 1u)) >> 16;  // RNE; inputs finite
  return (u16)r;
}

#define GLOAD_LDS16(gp, lp)                                                   \
  __builtin_amdgcn_global_load_lds(                                           \
      (const __attribute__((address_space(1))) void*)(gp),                    \
      (__attribute__((address_space(3))) void*)(lp), 16, 0, 0)

// ---------------- embedding: x = tok_emb[idx] + pos_emb ----------------
__global__ void k_embed(const int* __restrict__ idx, const float* __restrict__ tok,
                        const float* __restrict__ pos, float* __restrict__ x) {
  int row = blockIdx.x;            // b*1024 + t
  int t = row & 1023;
  int id = idx[row];
  int c = threadIdx.x * 4;
  float4 a = *(const float4*)(tok + (size_t)id * 1024 + c);
  float4 p = *(const float4*)(pos + (size_t)t * 1024 + c);
  float4 r{a.x + p.x, a.y + p.y, a.z + p.z, a.w + p.w};
  *(float4*)(x + (size_t)row * 1024 + c) = r;
}

// ---------------- layernorm (f32 in) -> bf16 out ----------------
__global__ void k_ln(const float* __restrict__ x, const float* __restrict__ sc,
                     const float* __restrict__ bi, u16* __restrict__ out) {
  int row = blockIdx.x;
  int t = threadIdx.x;
  const float* xr = x + (size_t)row * 1024;
  float4 v = *(const float4*)(xr + t * 4);
  float s = v.x + v.y + v.z + v.w;
  float ss = v.x * v.x + v.y * v.y + v.z * v.z + v.w * v.w;
  for (int d = 1; d < 64; d <<= 1) { s += __shfl_xor(s, d); ss += __shfl_xor(ss, d); }
  __shared__ float red[8];
  int wave = t >> 6, lane = t & 63;
  if (lane == 0) { red[wave] = s; red[wave + 4] = ss; }
  __syncthreads();
  s = red[0] + red[1] + red[2] + red[3];
  ss = red[4] + red[5] + red[6] + red[7];
  float mu = s * (1.0f / 1024.0f);
  float var = ss * (1.0f / 1024.0f) - mu * mu;
  float inv = rsqrtf(var + 1e-5f);
  float4 g = *(const float4*)(sc + t * 4);
  float4 b = *(const float4*)(bi + t * 4);
  u16x4 o;
  o[0] = f2bf((v.x - mu) * inv * g.x + b.x);
  o[1] = f2bf((v.y - mu) * inv * g.y + b.y);
  o[2] = f2bf((v.z - mu) * inv * g.z + b.z);
  o[3] = f2bf((v.w - mu) * inv * g.w + b.w);
  *(u16x4*)(out + (size_t)row * 1024 + t * 4) = o;
}

// ---------------- transpose+convert: f32 src[R][C] -> bf16 dst[C][R] ----------------
__launch_bounds__(1024)
__global__ void k_transpose(const float* __restrict__ src, u16* __restrict__ dst,
                            int R, int C) {
  __shared__ float tile[32][33];
  int tx = threadIdx.x, ty = threadIdx.y;
  int c = blockIdx.x * 32 + tx;
  int r = blockIdx.y * 32 + ty;
  tile[ty][tx] = src[(size_t)r * C + c];
  __syncthreads();
  int dr = blockIdx.x * 32 + ty;
  int dc = blockIdx.y * 32 + tx;
  dst[(size_t)dr * R + dc] = f2bf(tile[tx][ty]);
}

// ---------------- fused per-layer weight transpose (6 matrices, 1 launch) ----------
__launch_bounds__(1024)
__global__ void k_transpose_layer(const float* __restrict__ Wq, const float* __restrict__ Wk,
                                  const float* __restrict__ Wv, const float* __restrict__ Wo,
                                  const float* __restrict__ W1, const float* __restrict__ W2,
                                  u16* __restrict__ qkvT, u16* __restrict__ WoT,
                                  u16* __restrict__ W1T, u16* __restrict__ W2T) {
  int bid = blockIdx.x;
  const float* src; u16* dst; int R, C, bx, by;
  if (bid < 4096) {
    int which = bid >> 10, tile_i = bid & 1023;
    bx = tile_i & 31; by = tile_i >> 5; R = 1024; C = 1024;
    src = which == 0 ? Wq : which == 1 ? Wk : which == 2 ? Wv : Wo;
    dst = which == 3 ? WoT : qkvT + (size_t)which * 1048576;
  } else if (bid < 8192) {
    int tile_i = bid - 4096; bx = tile_i & 127; by = tile_i >> 7; R = 1024; C = 4096;
    src = W1; dst = W1T;
  } else {
    int tile_i = bid - 8192; bx = tile_i & 31; by = tile_i >> 5; R = 4096; C = 1024;
    src = W2; dst = W2T;
  }
  __shared__ float tile[32][33];
  int tx = threadIdx.x, ty = threadIdx.y;
  int c = bx * 32 + tx, r = by * 32 + ty;
  tile[ty][tx] = src[(size_t)r * C + c];
  __syncthreads();
  int dr = bx * 32 + ty, dc = by * 32 + tx;
  dst[(size_t)dr * R + dc] = f2bf(tile[tx][ty]);
}

// ---------------- GEMMs: C[M][N] = A[M][K](bf16) x Bt[N][K](bf16)^T ----------------
enum { EPI_QKV = 0, EPI_RES = 1, EPI_RELU = 2 };

// 128x128 tile, 2-phase pipelined (RELU gemm: 512 blocks)
template <int EPI>
__launch_bounds__(256, 4)
__global__ void k_gemm(const u16* __restrict__ A, const u16* __restrict__ Bt,
                       const float* __restrict__ bias, float* __restrict__ fout,
                       u16* __restrict__ bout, int M, int N, int K) {
  __shared__ alignas(16) u16 sm[2][2][128][32];
  const int t = threadIdx.x;
  const int wave = t >> 6, lane = t & 63;
  const int wm = wave >> 1, wn = wave & 1;
  const int g = lane >> 4, c = lane & 15;
  const int m0 = blockIdx.x * 128, n0 = blockIdx.y * 128;

  const int srow = wave * 32 + (lane >> 2);
  const int sseg = (lane & 3) * 8;
  const u16* gA = A + (size_t)(m0 + srow) * K + sseg;
  const u16* gB = Bt + (size_t)(n0 + srow) * K + sseg;

  f32x4 acc[4][4] = {};
  const int nK = K >> 5;
  int cur = 0;

#pragma unroll
  for (int p = 0; p < 2; ++p) {
    GLOAD_LDS16(gA + (size_t)p * 16 * K, &sm[0][0][wave * 32 + p * 16][0]);
    GLOAD_LDS16(gB + (size_t)p * 16 * K, &sm[0][1][wave * 32 + p * 16][0]);
  }
  __syncthreads();

  for (int kt = 0; kt < nK; ++kt) {
    if (kt + 1 < nK) {
      const int k0 = (kt + 1) << 5;
#pragma unroll
      for (int p = 0; p < 2; ++p) {
        GLOAD_LDS16(gA + k0 + (size_t)p * 16 * K, &sm[cur ^ 1][0][wave * 32 + p * 16][0]);
        GLOAD_LDS16(gB + k0 + (size_t)p * 16 * K, &sm[cur ^ 1][1][wave * 32 + p * 16][0]);
      }
    }
    bf16x8 af[4], bfr[4];
#pragma unroll
    for (int i = 0; i < 4; ++i) {
      af[i]  = *(const bf16x8*)&sm[cur][0][wm * 64 + i * 16 + c][g * 8];
      bfr[i] = *(const bf16x8*)&sm[cur][1][wn * 64 + i * 16 + c][g * 8];
    }
#pragma unroll
    for (int i = 0; i < 4; ++i)
#pragma unroll
      for (int j = 0; j < 4; ++j)
        acc[i][j] = __builtin_amdgcn_mfma_f32_16x16x32_bf16(af[i], bfr[j], acc[i][j], 0, 0, 0);
    __syncthreads();
    cur ^= 1;
  }

#pragma unroll
  for (int i = 0; i < 4; ++i)
#pragma unroll
    for (int j = 0; j < 4; ++j)
#pragma unroll
      for (int r = 0; r < 4; ++r) {
        int m = m0 + wm * 64 + i * 16 + g * 4 + r;
        int n = n0 + wn * 64 + j * 16 + c;
        float v = acc[i][j][r];
        if (EPI == EPI_RES) {
          fout[(size_t)m * N + n] += v + bias[n];
        } else if (EPI == EPI_RELU) {
          float u = v + bias[n];
          bout[(size_t)m * N + n] = f2bf(u > 0.f ? u : 0.f);
        }
      }
}

// 64x128 tile, 2-phase pipelined (QKV / residual gemms)
template <int EPI>
__launch_bounds__(256, 4)
__global__ void k_gemm64(const u16* __restrict__ A, const u16* __restrict__ Bt,
                         const float* __restrict__ bias, float* __restrict__ fout,
                         u16* __restrict__ bout, int M, int N, int K) {
  __shared__ alignas(16) u16 smem[12288];   // Al[2][64][32] | Bl[2][128][32]
#define AL(s, r, k) smem[(s)*2048 + (r)*32 + (k)]
#define BL(s, r, k) smem[4096 + (s)*4096 + (r)*32 + (k)]
  const int t = threadIdx.x;
  const int wave = t >> 6, lane = t & 63;
  const int wm = wave >> 1, wn = wave & 1;       // 2x2 waves: 32x64 out each
  const int g = lane >> 4, c = lane & 15;
  const int m0 = blockIdx.x * 64, n0 = blockIdx.y * 128;

  const int rwA = t >> 2, sgA = (t & 3) * 8;
  const u16* gA = A + (size_t)(m0 + rwA) * K + sgA;
  const u16* gB = Bt + (size_t)(n0 + rwA) * K + sgA;

  f32x4 acc[2][4] = {};
  const int nK = K >> 5;
  int cur = 0;

  GLOAD_LDS16(gA, &AL(0, rwA, 0));
#pragma unroll
  for (int p = 0; p < 2; ++p)
    GLOAD_LDS16(gB + (size_t)p * 64 * K, &BL(0, p * 64 + rwA, 0));
  __syncthreads();

  for (int kt = 0; kt < nK; ++kt) {
    if (kt + 1 < nK) {
      const int k0 = (kt + 1) << 5;
      GLOAD_LDS16(gA + k0, &AL(cur ^ 1, rwA, 0));
#pragma unroll
      for (int p = 0; p < 2; ++p)
        GLOAD_LDS16(gB + k0 + (size_t)p * 64 * K, &BL(cur ^ 1, p * 64 + rwA, 0));
    }
    bf16x8 af[2], bfr[4];
#pragma unroll
    for (int i = 0; i < 2; ++i)
      af[i] = *(const bf16x8*)&AL(cur, wm * 32 + i * 16 + c, g * 8);
#pragma unroll
    for (int j = 0; j < 4; ++j)
      bfr[j] = *(const bf16x8*)&BL(cur, wn * 64 + j * 16 + c, g * 8);
#pragma unroll
    for (int i = 0; i < 2; ++i)
#pragma unroll
      for (int j = 0; j < 4; ++j)
        acc[i][j] = __builtin_amdgcn_mfma_f32_16x16x32_bf16(af[i], bfr[j], acc[i][j], 0, 0, 0);
    __syncthreads();
    cur ^= 1;
  }

  if (EPI == EPI_QKV) {
    // stage bf16 tile [64][136] in (reused) LDS, then coalesced u16x8 stores
    u16 (*Ct)[136] = (u16(*)[136])smem;     // 8704 u16 <= 12288
#pragma unroll
    for (int i = 0; i < 2; ++i)
#pragma unroll
      for (int j = 0; j < 4; ++j)
#pragma unroll
        for (int r = 0; r < 4; ++r)
          Ct[wm * 32 + i * 16 + g * 4 + r][wn * 64 + j * 16 + c] = f2bf(acc[i][j][r]);
    __syncthreads();
    const int b = m0 >> 10, t0 = m0 & 1023;
    const int hh0 = (n0 >> 6) & 15, which = n0 >> 10;
    u16* obase = bout + (size_t)which * 2097152;
#pragma unroll
    for (int itr = 0; itr < 4; ++itr) {
      int idx2 = itr * 256 + t;       // 0..1023 chunks of 16B
      int s = idx2 >> 9;              // head 0/1
      int tt = (idx2 >> 3) & 63;
      int seg = idx2 & 7;
      u16x8 vv = *(const u16x8*)&Ct[tt][s * 64 + seg * 8];
      *(u16x8*)(obase + ((size_t)(b * 16 + hh0 + s) * 1024 + (t0 + tt)) * 64 + seg * 8) = vv;
    }
    return;
  }

#pragma unroll
  for (int i = 0; i < 2; ++i)
#pragma unroll
    for (int j = 0; j < 4; ++j)
#pragma unroll
      for (int r = 0; r < 4; ++r) {
        int m = m0 + wm * 32 + i * 16 + g * 4 + r;
        int n = n0 + wn * 64 + j * 16 + c;
        if (EPI == EPI_RES) fout[(size_t)m * N + n] += acc[i][j][r] + bias[n];
      }
#undef AL
#undef BL
}

// ---------------- GEMM 256x256 8-phase (LM head, f32+bias out) ----------------
// Staging pairs issued early (>=3 phases before their VM4); builtin barrier
// bracketed by compiler fences; quadrant order (0,0)(0,1)(1,1)(1,0) with
// persistent frag regs. Rule #20: all acc indices static.

#define BAR                                                                    \
  {                                                                            \
    asm volatile("" ::: "memory");                                             \
    __builtin_amdgcn_s_barrier();                                              \
    asm volatile("" ::: "memory");                                             \
  }
#define VM4 asm volatile("s_waitcnt vmcnt(4)" ::: "memory")
#define VM0 asm volatile("s_waitcnt vmcnt(0)" ::: "memory")

#define STGA(sl, hf, kt)                                                       \
  {                                                                            \
    _Pragma("unroll") for (int p = 0; p < 2; ++p) {                            \
      int idx = p * 512 + t, rw = idx >> 3, sg = idx & 7;                      \
      GLOAD_LDS16(A + (size_t)(m0 + (hf)*128 + rw) * K + (kt)*64 +             \
                      ((sg ^ (rw & 7)) << 3),                                  \
                  &Alds[sl][(hf)*128 + rw][sg << 3]);                          \
    }                                                                          \
  }
#define STGB(sl, hf, kt)                                                       \
  {                                                                            \
    _Pragma("unroll") for (int p = 0; p < 2; ++p) {                            \
      int idx = p * 512 + t, rw = idx >> 3, sg = idx & 7;                      \
      GLOAD_LDS16(Bt + (size_t)(n0 + (hf)*128 + rw) * K + (kt)*64 +            \
                      ((sg ^ (rw & 7)) << 3),                                  \
                  &Blds[sl][(hf)*128 + rw][sg << 3]);                          \
    }                                                                          \
  }

#define LMLOAD_A(sl, mh)                                                       \
  _Pragma("unroll") for (int i = 0; i < 4; ++i) {                              \
    int ra = (mh)*128 + wm * 64 + i * 16 + c;                                  \
    _Pragma("unroll") for (int ks = 0; ks < 2; ++ks)                           \
      af[i][ks] = *(const bf16x8*)&Alds[sl][ra][(((ks << 2) | g) ^ (ra & 7)) << 3]; \
  }
#define LMLOAD_B(sl, nh, bfv)                                                  \
  _Pragma("unroll") for (int j = 0; j < 2; ++j) {                              \
    int rb = (nh)*128 + wn * 32 + j * 16 + c;                                  \
    _Pragma("unroll") for (int ks = 0; ks < 2; ++ks)                           \
      bfv[j][ks] = *(const bf16x8*)&Blds[sl][rb][(((ks << 2) | g) ^ (rb & 7)) << 3]; \
  }
#define LMMMA(mh, nh, bfv)                                                     \
  __builtin_amdgcn_s_setprio(1);                                               \
  _Pragma("unroll") for (int i = 0; i < 4; ++i)                                \
    _Pragma("unroll") for (int j = 0; j < 2; ++j)                              \
      _Pragma("unroll") for (int ks = 0; ks < 2; ++ks)                         \
        acc[mh][nh][i][j] = __builtin_amdgcn_mfma_f32_16x16x32_bf16(           \
            af[i][ks], bfv[j][ks], acc[mh][nh][i][j], 0, 0, 0);                \
  __builtin_amdgcn_s_setprio(0);

__launch_bounds__(512, 2)
__global__ void k_gemm_lm(const u16* __restrict__ A, const u16* __restrict__ Bt,
                          const float* __restrict__ bias, float* __restrict__ fout,
                          int M, int N, int K) {
  __shared__ alignas(16) u16 Alds[2][256][64];
  __shared__ alignas(16) u16 Blds[2][256][64];
  const int t = threadIdx.x;
  const int wid = t >> 6, lane = t & 63;
  const int wm = wid >> 2, wn = wid & 3;
  const int g = lane >> 4, c = lane & 15;

  int bid = blockIdx.x;
  int swz = (bid & 7) * 125 + (bid >> 3);
  const int m0 = (swz & 7) * 256, n0 = (swz >> 3) * 256;

  f32x4 acc[2][2][4][2] = {};
  bf16x8 af[4][2], bf0[2][2], bf1[2][2];

  const int nK = K >> 6;
  const int nIter = nK >> 1;

  STGA(0, 0, 0); STGB(0, 0, 0);
  STGA(0, 1, 0); STGB(0, 1, 0);
  STGA(1, 0, 1); STGB(1, 0, 1);
  VM4;
  BAR;

  for (int it = 0; it < nIter; ++it) {
    const int t1 = 2 * it + 1, t2 = 2 * it + 2, t3 = 2 * it + 3;
    const bool more = (it + 1 < nIter);
    // ---- slot 0 = tile 2it ----
    LMLOAD_A(0, 0); LMLOAD_B(0, 0, bf0);
    STGA(1, 1, t1); STGB(1, 1, t1);
    BAR; LMMMA(0, 0, bf0); BAR;
    LMLOAD_B(0, 1, bf1);
    BAR; LMMMA(0, 1, bf1); BAR;
    LMLOAD_A(0, 1);
    if (more) { STGA(0, 0, t2); }
    BAR; LMMMA(1, 1, bf1); BAR;
    if (more) { STGB(0, 0, t2); BAR; LMMMA(1, 0, bf0); VM4; BAR; }
    else      { BAR; LMMMA(1, 0, bf0); VM0; BAR; }
    // ---- slot 1 = tile 2it+1 ----
    LMLOAD_A(1, 0); LMLOAD_B(1, 0, bf0);
    if (more) { STGA(0, 1, t2); STGB(0, 1, t2); }
    BAR; LMMMA(0, 0, bf0); BAR;
    LMLOAD_B(1, 1, bf1);
    BAR; LMMMA(0, 1, bf1); BAR;
    LMLOAD_A(1, 1);
    if (more) { STGA(1, 0, t3); STGB(1, 0, t3); }
    BAR; LMMMA(1, 1, bf1); BAR;
    if (more) { BAR; LMMMA(1, 0, bf0); VM4; BAR; }
    else      { BAR; LMMMA(1, 0, bf0); VM0; BAR; }
  }

  // epilogue: LDS-staged coalesced f32 stores; fully unrolled (static acc idx)
  float (*stile)[260] = (float(*)[260])&Alds[0][0][0];
#pragma unroll
  for (int RG = 0; RG < 8; ++RG) {
    const int mh = RG >> 2, wsel = (RG >> 1) & 1, ih = RG & 1;
    if (wm == wsel) {
#pragma unroll
      for (int i2 = 0; i2 < 2; ++i2)
#pragma unroll
        for (int nh = 0; nh < 2; ++nh)
#pragma unroll
          for (int j = 0; j < 2; ++j)
#pragma unroll
            for (int r = 0; r < 4; ++r) {
              float v = acc[mh][nh][ih * 2 + i2][j][r];
              stile[i2 * 16 + g * 4 + r][nh * 128 + wn * 32 + j * 16 + c] = v;
            }
    }
    __syncthreads();
    {
      int row = t >> 4, seg = t & 15;
      int m = m0 + RG * 32 + row;
      float* dst = fout + (size_t)m * N + n0 + seg * 16;
      const float* bsrc = bias + n0 + seg * 16;
#pragma unroll
      for (int q = 0; q < 4; ++q) {
        float4 v = *(const float4*)&stile[row][seg * 16 + q * 4];
        float4 bb = *(const float4*)&bsrc[q * 4];
        float4 o{v.x + bb.x, v.y + bb.y, v.z + bb.z, v.w + bb.w};
        *(float4*)(dst + q * 4) = o;
      }
    }
    __syncthreads();
  }
}

// ---------------- flash attention: 1 wave per (bh, 32 q-rows) ----------------
__launch_bounds__(64)
__global__ void k_attn(const u16* __restrict__ Q, const u16* __restrict__ Kb,
                       const u16* __restrict__ V, u16* __restrict__ O) {
  const int qb = blockIdx.x;       // 0..31
  const int bh = blockIdx.y;       // 0..31
  const int lane = threadIdx.x;
  const int g = lane >> 4, c = lane & 15;
  const int q0 = qb << 5;
  const u16* Qh = Q + (size_t)bh * 65536;
  const u16* Kh = Kb + (size_t)bh * 65536;
  const u16* Vh = V + (size_t)bh * 65536;

  __shared__ u16 Vt[64][40];   // [d][key32]
  __shared__ u16 Pl[32][40];   // [q][key32]

  bf16x8 aq[2][2];
#pragma unroll
  for (int qt = 0; qt < 2; ++qt) {
    aq[qt][0] = *(const bf16x8*)(Qh + (q0 + qt * 16 + c) * 64 + g * 8);
    aq[qt][1] = *(const bf16x8*)(Qh + (q0 + qt * 16 + c) * 64 + 32 + g * 8);
  }

  f32x4 Oacc[2][4] = {};
  float Mr[2][4], Lr[2][4] = {};
#pragma unroll
  for (int qt = 0; qt < 2; ++qt)
#pragma unroll
    for (int r = 0; r < 4; ++r) Mr[qt][r] = -1e30f;

  const int nIt = qb + 1;
  for (int it = 0; it < nIt; ++it) {
    const int k0 = it << 5;
    bf16x8 b0 = *(const bf16x8*)(Kh + (k0 + c) * 64 + g * 8);
    bf16x8 b1 = *(const bf16x8*)(Kh + (k0 + c) * 64 + 32 + g * 8);
    bf16x8 b2 = *(const bf16x8*)(Kh + (k0 + 16 + c) * 64 + g * 8);
    bf16x8 b3 = *(const bf16x8*)(Kh + (k0 + 16 + c) * 64 + 32 + g * 8);
    f32x4 S[2][2];
#pragma unroll
    for (int qt = 0; qt < 2; ++qt) {
      f32x4 z = {};
      S[qt][0] = __builtin_amdgcn_mfma_f32_16x16x32_bf16(
          aq[qt][1], b1, __builtin_amdgcn_mfma_f32_16x16x32_bf16(aq[qt][0], b0, z, 0, 0, 0), 0, 0, 0);
      S[qt][1] = __builtin_amdgcn_mfma_f32_16x16x32_bf16(
          aq[qt][1], b3, __builtin_amdgcn_mfma_f32_16x16x32_bf16(aq[qt][0], b2, z, 0, 0, 0), 0, 0, 0);
    }
    // stage V transposed: Vt[d][key] (shared across both q-tiles)
#pragma unroll
    for (int p = 0; p < 4; ++p) {
      int key = (p << 3) + (lane >> 3);
      int d0 = (lane & 7) << 3;
      u16x8 vv = *(const u16x8*)(Vh + (size_t)(k0 + key) * 64 + d0);
#pragma unroll
      for (int j = 0; j < 8; ++j) Vt[d0 + j][key] = vv[j];
    }
    const float scale = 0.125f;
#pragma unroll
    for (int qt = 0; qt < 2; ++qt)
#pragma unroll
      for (int r = 0; r < 4; ++r) {
        int q = q0 + qt * 16 + (g << 2) + r;
        float s0 = (k0 + c <= q) ? S[qt][0][r] * scale : -1e30f;
        float s1 = (k0 + 16 + c <= q) ? S[qt][1][r] * scale : -1e30f;
        float m = fmaxf(s0, s1);
        m = fmaxf(m, __shfl_xor(m, 1));
        m = fmaxf(m, __shfl_xor(m, 2));
        m = fmaxf(m, __shfl_xor(m, 4));
        m = fmaxf(m, __shfl_xor(m, 8));
        float mnew = fmaxf(Mr[qt][r], m);
        float p0 = __expf(s0 - mnew);
        float p1 = __expf(s1 - mnew);
        float rs = p0 + p1;
        rs += __shfl_xor(rs, 1);
        rs += __shfl_xor(rs, 2);
        rs += __shfl_xor(rs, 4);
        rs += __shfl_xor(rs, 8);
        float alpha = __expf(Mr[qt][r] - mnew);
        Lr[qt][r] = Lr[qt][r] * alpha + rs;
        Mr[qt][r] = mnew;
#pragma unroll
        for (int nb = 0; nb < 4; ++nb) Oacc[qt][nb][r] *= alpha;
        Pl[qt * 16 + (g << 2) + r][c] = f2bf(p0);
        Pl[qt * 16 + (g << 2) + r][16 + c] = f2bf(p1);
      }
    // PV (single wave: DS in-order, no barrier); V-frags reused across q-tiles
#pragma unroll
    for (int nb = 0; nb < 4; ++nb) {
      bf16x8 bv = *(const bf16x8*)&Vt[nb * 16 + c][g * 8];
#pragma unroll
      for (int qt = 0; qt < 2; ++qt) {
        bf16x8 ap = *(const bf16x8*)&Pl[qt * 16 + c][g * 8];
        Oacc[qt][nb] = __builtin_amdgcn_mfma_f32_16x16x32_bf16(ap, bv, Oacc[qt][nb], 0, 0, 0);
      }
    }
  }
  const int b = bh >> 4, hh = bh & 15;
#pragma unroll
  for (int qt = 0; qt < 2; ++qt)
#pragma unroll
    for (int r = 0; r < 4; ++r) {
      int tt = q0 + qt * 16 + (g << 2) + r;
      float invl = 1.0f / Lr[qt][r];
#pragma unroll
      for (int nb = 0; nb < 4; ++nb) {
        int d = nb * 16 + c;
        O[((size_t)(b * 1024 + tt)) * 1024 + hh * 64 + d] = f2bf(Oacc[qt][nb][r] * invl);
      }
    }
}

// ---------------- launch ----------------
extern "C" void kernel_launch(void* const* d_in, const int* in_sizes, int n_in,
                              void* d_out, int out_size, void* d_ws, size_t ws_size,
                              hipStream_t stream) {
  const int*   idx  = (const int*)d_in[0];
  const float* tok  = (const float*)d_in[1];
  const float* pos  = (const float*)d_in[2];
  const float* Wq   = (const float*)d_in[3];
  const float* Wk   = (const float*)d_in[4];
  const float* Wv   = (const float*)d_in[5];
  const float* Wo   = (const float*)d_in[6];
  const float* bo   = (const float*)d_in[7];
  const float* ln1s = (const float*)d_in[8];
  const float* ln1b = (const float*)d_in[9];
  const float* ln2s = (const float*)d_in[10];
  const float* ln2b = (const float*)d_in[11];
  const float* W1   = (const float*)d_in[12];
  const float* b1   = (const float*)d_in[13];
  const float* W2   = (const float*)d_in[14];
  const float* b2   = (const float*)d_in[15];
  const float* lnfs = (const float*)d_in[16];
  const float* lnfb = (const float*)d_in[17];
  const float* Wlm  = (const float*)d_in[18];
  const float* blm  = (const float*)d_in[19];
  float* out = (float*)d_out;

  char* w = (char*)d_ws;
  auto alloc = [&](size_t bytes) {
    char* p = w;
    w += (bytes + 255) & ~(size_t)255;
    return p;
  };
  float* x  = (float*)alloc(2048ull * 1024 * 4);
  u16* h    = (u16*)alloc(2048ull * 1024 * 2);
  u16* qkv  = (u16*)alloc(3ull * 2097152 * 2);
  u16* o    = (u16*)alloc(2048ull * 1024 * 2);
  u16* a1   = (u16*)alloc(2048ull * 4096 * 2);
  u16* arena = (u16*)alloc(32000ull * 1024 * 2);

  dim3 b32(32, 32, 1);

  k_embed<<<2048, 256, 0, stream>>>(idx, tok, pos, x);

  for (int l = 0; l < 4; ++l) {
    u16* qkvT = arena;
    u16* WoT  = arena + 3ull * 1048576;
    u16* W1T  = arena + 4ull * 1048576;
    u16* W2T  = arena + 8ull * 1048576;
    k_transpose_layer<<<12288, b32, 0, stream>>>(
        Wq + (size_t)l * 1048576, Wk + (size_t)l * 1048576,
        Wv + (size_t)l * 1048576, Wo + (size_t)l * 1048576,
        W1 + (size_t)l * 4194304, W2 + (size_t)l * 4194304,
        qkvT, WoT, W1T, W2T);

    k_ln<<<2048, 256, 0, stream>>>(x, ln1s + l * 1024, ln1b + l * 1024, h);
    k_gemm64<EPI_QKV><<<dim3(32, 24), 256, 0, stream>>>(h, qkvT, nullptr, nullptr, qkv,
                                                        2048, 3072, 1024);
    k_attn<<<dim3(32, 32), 64, 0, stream>>>(qkv, qkv + 2097152, qkv + 2 * 2097152, o);
    k_gemm64<EPI_RES><<<dim3(32, 8), 256, 0, stream>>>(o, WoT, bo + l * 1024, x, nullptr,
                                                       2048, 1024, 1024);
    k_ln<<<2048, 256, 0, stream>>>(x, ln2s + l * 1024, ln2b + l * 1024, h);
    k_gemm<EPI_RELU><<<dim3(16, 32), 256, 0, stream>>>(h, W1T, b1 + l * 4096, nullptr, a1,
                                                       2048, 4096, 1024);
    k_gemm64<EPI_RES><<<dim3(32, 8), 256, 0, stream>>>(a1, W2T, b2 + l * 1024, x, nullptr,
                                                       2048, 1024, 4096);
  }

  k_ln<<<2048, 256, 0, stream>>>(x, lnfs, lnfb, h);
  k_transpose<<<dim3(1000, 32), b32, 0, stream>>>(Wlm, arena, 1024, 32000);
  k_gemm_lm<<<1000, 512, 0, stream>>>(h, arena, blm, out, 2048, 32000, 1024);
}